// Round 1
// baseline (864.070 us; speedup 1.0000x reference)
//
#include <hip/hip_runtime.h>
#include <cstdint>

// Reference geometry (fixed problem)
constexpr int B_ = 4, H_ = 8, D_ = 64, L_ = 4096;
constexpr int BH = B_ * H_;          // 32
constexpr int U_PART = 25;           // FACTOR * ceil(log(64))
constexpr int TOPU = 45;             // FACTOR * ceil(log(4096))

// JAX >= 0.4.36 defaults jax_threefry_partitionable=True. If validation fails
// with O(1) absmax, flip this to 0 (legacy counter layout) next round.
#define JAX_THREEFRY_PARTITIONABLE 1

// ---------------- Threefry-2x32 (exact JAX semantics) ----------------
__host__ __device__ inline void tf2x32(uint32_t k0, uint32_t k1,
                                       uint32_t x0, uint32_t x1,
                                       uint32_t& y0, uint32_t& y1) {
  const uint32_t ks2 = k0 ^ k1 ^ 0x1BD11BDAu;
  uint32_t v0 = x0 + k0, v1 = x1 + k1;
#define RND(r) { v0 += v1; v1 = (v1 << (r)) | (v1 >> (32 - (r))); v1 ^= v0; }
  RND(13) RND(15) RND(26) RND(6)
  v0 += k1; v1 += ks2 + 1u;
  RND(17) RND(29) RND(16) RND(24)
  v0 += ks2; v1 += k0 + 2u;
  RND(13) RND(15) RND(26) RND(6)
  v0 += k0; v1 += k1 + 3u;
  RND(17) RND(29) RND(16) RND(24)
  v0 += k1; v1 += ks2 + 4u;
  RND(13) RND(15) RND(26) RND(6)
  v0 += ks2; v1 += k0 + 5u;
#undef RND
  y0 = v0; y1 = v1;
}

// idx[i] for i in [0, 4096*25): index_sample.flat
__global__ __launch_bounds__(256) void sample_idx_kernel(int* __restrict__ idx,
                                                         uint32_t k2a, uint32_t k2b) {
#if JAX_THREEFRY_PARTITIONABLE
  int i = blockIdx.x * 256 + threadIdx.x;
  if (i >= L_ * U_PART) return;
  uint32_t y0, y1;
  tf2x32(k2a, k2b, 0u, (uint32_t)i, y0, y1);
  idx[i] = (int)((y0 ^ y1) & 4095u);
#else
  // legacy: counts iota(102400) split into halves; block j = (j, j+51200)
  int j = blockIdx.x * 256 + threadIdx.x;
  const int half = (L_ * U_PART) / 2;   // 51200
  if (j >= half) return;
  uint32_t y0, y1;
  tf2x32(k2a, k2b, (uint32_t)j, (uint32_t)(j + half), y0, y1);
  idx[j] = (int)(y0 & 4095u);
  idx[j + half] = (int)(y1 & 4095u);
#endif
}

// ---------------- Transpose + scale: (BH, D, L) -> (BH, L, D) ----------------
__global__ __launch_bounds__(256) void transpose_scale(
    const float* __restrict__ q, const float* __restrict__ k, const float* __restrict__ v,
    float* __restrict__ qt, float* __restrict__ kt, float* __restrict__ vt) {
  const float* src; float* dst; float scale;
  if (blockIdx.z == 0)      { src = q; dst = qt; scale = 1.0f / 512.0f; }
  else if (blockIdx.z == 1) { src = k; dst = kt; scale = 1.0f / 64.0f; }
  else                      { src = v; dst = vt; scale = 1.0f / 64.0f; }
  const int bh = blockIdx.y;
  const int l0 = blockIdx.x * 64;
  __shared__ float tile[64][65];
  const float* s = src + (size_t)bh * D_ * L_;
  float* d = dst + (size_t)bh * L_ * D_;
  const int t = threadIdx.x;
#pragma unroll
  for (int i = 0; i < 16; i++) {
    int li = i * 256 + t;          // 0..4095
    int dd = li >> 6, ll = li & 63;
    tile[dd][ll] = s[(size_t)dd * L_ + l0 + ll] * scale;
  }
  __syncthreads();
#pragma unroll
  for (int i = 0; i < 16; i++) {
    int li = i * 256 + t;
    int ll = li >> 6, dd = li & 63;
    d[(size_t)(l0 + ll) * D_ + dd] = tile[dd][ll];
  }
}

// ---------------- M[b,h,l] = max_s QK - sum_s QK / 4096 ----------------
__global__ __launch_bounds__(256) void m_kernel(const float* __restrict__ qt,
                                                const float* __restrict__ kt,
                                                const int* __restrict__ idx,
                                                float* __restrict__ M) {
  const int wave = threadIdx.x >> 6, lane = threadIdx.x & 63;
  const int gl = blockIdx.x * 4 + wave;       // 0..BH*L-1
  const int bh = gl >> 12, l = gl & (L_ - 1);
  const float* qtb = qt + (size_t)bh * L_ * D_;
  const float* ktb = kt + (size_t)bh * L_ * D_;
  const float qv = qtb[(size_t)l * D_ + lane];
  const int* ip = idx + l * U_PART;
  float mx = -INFINITY, sm = 0.0f;
#pragma unroll 5
  for (int s = 0; s < U_PART; s++) {
    int ki = ip[s];
    float p = qv * ktb[(size_t)ki * D_ + lane];
#pragma unroll
    for (int off = 32; off; off >>= 1) p += __shfl_xor(p, off, 64);
    mx = fmaxf(mx, p);
    sm += p;
  }
  if (lane == 0) M[gl] = mx - sm * (1.0f / 4096.0f);
}

// ---------------- top-45 indices per (b,h) ----------------
__global__ __launch_bounds__(256) void topk_kernel(const float* __restrict__ M,
                                                   int* __restrict__ mtop) {
  __shared__ float sv[L_];
  __shared__ float red_v[4];
  __shared__ int red_i[4];
  const int bh = blockIdx.x, t = threadIdx.x;
  const float* Mb = M + (size_t)bh * L_;
  for (int i = t; i < L_; i += 256) sv[i] = Mb[i];
  __syncthreads();
  for (int it = 0; it < TOPU; it++) {
    float bv = -INFINITY; int bi = 0x7fffffff;
    for (int i = t; i < L_; i += 256) {
      float v = sv[i];
      if (v > bv || (v == bv && i < bi)) { bv = v; bi = i; }
    }
#pragma unroll
    for (int off = 32; off; off >>= 1) {
      float ov = __shfl_xor(bv, off, 64);
      int   oi = __shfl_xor(bi, off, 64);
      if (ov > bv || (ov == bv && oi < bi)) { bv = ov; bi = oi; }
    }
    if ((t & 63) == 0) { red_v[t >> 6] = bv; red_i[t >> 6] = bi; }
    __syncthreads();
    if (t == 0) {
      for (int w = 1; w < 4; w++)
        if (red_v[w] > bv || (red_v[w] == bv && red_i[w] < bi)) { bv = red_v[w]; bi = red_i[w]; }
      mtop[bh * TOPU + it] = bi;
      sv[bi] = -INFINITY;
    }
    __syncthreads();
  }
}

// ---------------- out[bh,d,l] = cumsum_l v[bh,d,l] / 64 ----------------
__global__ __launch_bounds__(256) void cumsum_kernel(const float* __restrict__ v,
                                                     float* __restrict__ out) {
  const int row = blockIdx.x;                 // BH*D rows
  const float* src = v + (size_t)row * L_;
  float* dst = out + (size_t)row * L_;
  const int t = threadIdx.x;
  float vals[16];
  const float4* s4 = (const float4*)(src + t * 16);
#pragma unroll
  for (int i = 0; i < 4; i++) {
    float4 x = s4[i];
    vals[4 * i + 0] = x.x; vals[4 * i + 1] = x.y;
    vals[4 * i + 2] = x.z; vals[4 * i + 3] = x.w;
  }
  float run = 0.0f;
#pragma unroll
  for (int i = 0; i < 16; i++) { run += vals[i] * (1.0f / 64.0f); vals[i] = run; }
  // inclusive scan of per-thread totals
  float x = run;
#pragma unroll
  for (int off = 1; off < 64; off <<= 1) {
    float y = __shfl_up(x, off, 64);
    if ((t & 63) >= off) x += y;
  }
  __shared__ float wtot[4];
  if ((t & 63) == 63) wtot[t >> 6] = x;
  __syncthreads();
  float woff = 0.0f;
  for (int w = 0; w < (t >> 6); w++) woff += wtot[w];
  const float excl = x - run + woff;
#pragma unroll
  for (int i = 0; i < 16; i++) vals[i] += excl;
  float4* d4 = (float4*)(dst + t * 16);
#pragma unroll
  for (int i = 0; i < 4; i++)
    d4[i] = make_float4(vals[4 * i], vals[4 * i + 1], vals[4 * i + 2], vals[4 * i + 3]);
}

// ---------------- attention update for the 45 selected rows ----------------
__global__ __launch_bounds__(256) void update_kernel(const float* __restrict__ qt,
                                                     const float* __restrict__ kt,
                                                     const float* __restrict__ vt,
                                                     const int* __restrict__ mtop,
                                                     float* __restrict__ out) {
  const int bh = blockIdx.x / TOPU;
  const int sel = mtop[blockIdx.x];
  const float* qtb = qt + (size_t)bh * L_ * D_;
  const float* ktb = kt + (size_t)bh * L_ * D_;
  const float* vtb = vt + (size_t)bh * L_ * D_;
  const int t = threadIdx.x;
  __shared__ float qs[64];
  __shared__ float e[L_];
  __shared__ float red[8];
  __shared__ float upd_part[4][64];
  if (t < 64) qs[t] = qtb[(size_t)sel * D_ + t];
  __syncthreads();
  const int n = sel + 1;                      // causal: k <= sel
  float lmax = -INFINITY;
  for (int k = t; k < n; k += 256) {
    const float4* kr = (const float4*)(ktb + (size_t)k * D_);
    float acc = 0.0f;
#pragma unroll
    for (int i = 0; i < 16; i++) {
      float4 kk = kr[i];
      acc += qs[4 * i] * kk.x + qs[4 * i + 1] * kk.y +
             qs[4 * i + 2] * kk.z + qs[4 * i + 3] * kk.w;
    }
    acc *= (1.0f / 512.0f);
    e[k] = acc;
    lmax = fmaxf(lmax, acc);
  }
#pragma unroll
  for (int off = 32; off; off >>= 1) lmax = fmaxf(lmax, __shfl_xor(lmax, off, 64));
  if ((t & 63) == 0) red[t >> 6] = lmax;
  __syncthreads();
  const float gmax = fmaxf(fmaxf(red[0], red[1]), fmaxf(red[2], red[3]));
  float lsum = 0.0f;
  for (int k = t; k < n; k += 256) {
    float ex = expf(e[k] - gmax);
    e[k] = ex;
    lsum += ex;
  }
#pragma unroll
  for (int off = 32; off; off >>= 1) lsum += __shfl_xor(lsum, off, 64);
  __syncthreads();
  if ((t & 63) == 0) red[4 + (t >> 6)] = lsum;
  __syncthreads();
  const float inv = 1.0f / (red[4] + red[5] + red[6] + red[7]);
  const int w = t >> 6, d = t & 63;
  float acc = 0.0f;
  for (int k = w; k < n; k += 4) acc += e[k] * vtb[(size_t)k * D_ + d];
  upd_part[w][d] = acc;
  __syncthreads();
  if (t < 64) {
    float s = upd_part[0][t] + upd_part[1][t] + upd_part[2][t] + upd_part[3][t];
    out[((size_t)bh * D_ + t) * L_ + sel] = s * inv;
  }
}

extern "C" void kernel_launch(void* const* d_in, const int* in_sizes, int n_in,
                              void* d_out, int out_size, void* d_ws, size_t ws_size,
                              hipStream_t stream) {
  const float* q = (const float*)d_in[0];
  const float* k = (const float*)d_in[1];
  const float* v = (const float*)d_in[2];
  float* out = (float*)d_out;

  const size_t NT = (size_t)BH * L_ * D_;     // 8388608 floats per tensor
  float* qt = (float*)d_ws;
  float* kt = qt + NT;
  float* vt = kt + NT;
  float* M  = vt + NT;                         // BH*L floats
  int* idx  = (int*)(M + (size_t)BH * L_);     // 4096*25 ints
  int* mtop = idx + L_ * U_PART;               // BH*45 ints

  // k2 = second key from split(key(42)) -- computed on host (pure CPU math)
  uint32_t k2a, k2b;
#if JAX_THREEFRY_PARTITIONABLE
  // foldlike split: blocks (0,0) and (0,1); key_1 = (y0,y1) of block (0,1)
  tf2x32(0u, 42u, 0u, 1u, k2a, k2b);
#else
  // original split: counts iota(4): blocks (0,2),(1,3); k2 = (y1(0,2), y1(1,3))
  uint32_t a0, a1, b0, b1;
  tf2x32(0u, 42u, 0u, 2u, a0, a1);
  tf2x32(0u, 42u, 1u, 3u, b0, b1);
  k2a = a1; k2b = b1;
#endif

  transpose_scale<<<dim3(L_ / 64, BH, 3), 256, 0, stream>>>(q, k, v, qt, kt, vt);
#if JAX_THREEFRY_PARTITIONABLE
  sample_idx_kernel<<<(L_ * U_PART + 255) / 256, 256, 0, stream>>>(idx, k2a, k2b);
#else
  sample_idx_kernel<<<(L_ * U_PART / 2 + 255) / 256, 256, 0, stream>>>(idx, k2a, k2b);
#endif
  m_kernel<<<BH * L_ / 4, 256, 0, stream>>>(qt, kt, idx, M);
  topk_kernel<<<BH, 256, 0, stream>>>(M, mtop);
  cumsum_kernel<<<BH * D_, 256, 0, stream>>>(v, out);
  update_kernel<<<BH * TOPU, 256, 0, stream>>>(qt, kt, vt, mtop, out);
}

// Round 2
// 854.234 us; speedup vs baseline: 1.0115x; 1.0115x over previous
//
#include <hip/hip_runtime.h>
#include <cstdint>

// Reference geometry (fixed problem)
constexpr int B_ = 4, H_ = 8, D_ = 64, L_ = 4096;
constexpr int BH = B_ * H_;          // 32
constexpr int U_PART = 25;           // FACTOR * ceil(log(64))
constexpr int TOPU = 45;             // FACTOR * ceil(log(4096))
constexpr int CHUNK = 512;           // keys per partial-update block
constexpr int NCH = L_ / CHUNK;      // 8 chunks
constexpr int PSTRIDE = 66;          // acc[64], max, sum

#define JAX_THREEFRY_PARTITIONABLE 1

// ---------------- Threefry-2x32 (exact JAX semantics) ----------------
__host__ __device__ inline void tf2x32(uint32_t k0, uint32_t k1,
                                       uint32_t x0, uint32_t x1,
                                       uint32_t& y0, uint32_t& y1) {
  const uint32_t ks2 = k0 ^ k1 ^ 0x1BD11BDAu;
  uint32_t v0 = x0 + k0, v1 = x1 + k1;
#define RND(r) { v0 += v1; v1 = (v1 << (r)) | (v1 >> (32 - (r))); v1 ^= v0; }
  RND(13) RND(15) RND(26) RND(6)
  v0 += k1; v1 += ks2 + 1u;
  RND(17) RND(29) RND(16) RND(24)
  v0 += ks2; v1 += k0 + 2u;
  RND(13) RND(15) RND(26) RND(6)
  v0 += k0; v1 += k1 + 3u;
  RND(17) RND(29) RND(16) RND(24)
  v0 += k1; v1 += ks2 + 4u;
  RND(13) RND(15) RND(26) RND(6)
  v0 += ks2; v1 += k0 + 5u;
#undef RND
  y0 = v0; y1 = v1;
}

__global__ __launch_bounds__(256) void sample_idx_kernel(int* __restrict__ idx,
                                                         uint32_t k2a, uint32_t k2b) {
#if JAX_THREEFRY_PARTITIONABLE
  int i = blockIdx.x * 256 + threadIdx.x;
  if (i >= L_ * U_PART) return;
  uint32_t y0, y1;
  tf2x32(k2a, k2b, 0u, (uint32_t)i, y0, y1);
  idx[i] = (int)((y0 ^ y1) & 4095u);
#else
  int j = blockIdx.x * 256 + threadIdx.x;
  const int half = (L_ * U_PART) / 2;   // 51200
  if (j >= half) return;
  uint32_t y0, y1;
  tf2x32(k2a, k2b, (uint32_t)j, (uint32_t)(j + half), y0, y1);
  idx[j] = (int)(y0 & 4095u);
  idx[j + half] = (int)(y1 & 4095u);
#endif
}

// ---------------- Transpose + scale: (BH, D, L) -> (BH, L, D) ----------------
__global__ __launch_bounds__(256) void transpose_scale(
    const float* __restrict__ q, const float* __restrict__ k, const float* __restrict__ v,
    float* __restrict__ qt, float* __restrict__ kt, float* __restrict__ vt) {
  const float* src; float* dst; float scale;
  if (blockIdx.z == 0)      { src = q; dst = qt; scale = 1.0f / 512.0f; }
  else if (blockIdx.z == 1) { src = k; dst = kt; scale = 1.0f / 64.0f; }
  else                      { src = v; dst = vt; scale = 1.0f / 64.0f; }
  const int bh = blockIdx.y;
  const int l0 = blockIdx.x * 64;
  __shared__ float tile[64][65];
  const float* s = src + (size_t)bh * D_ * L_;
  float* d = dst + (size_t)bh * L_ * D_;
  const int t = threadIdx.x;
#pragma unroll
  for (int i = 0; i < 16; i++) {
    int li = i * 256 + t;          // 0..4095
    int dd = li >> 6, ll = li & 63;
    tile[dd][ll] = s[(size_t)dd * L_ + l0 + ll] * scale;
  }
  __syncthreads();
#pragma unroll
  for (int i = 0; i < 16; i++) {
    int li = i * 256 + t;
    int ll = li >> 6, dd = li & 63;
    d[(size_t)(l0 + ll) * D_ + dd] = tile[dd][ll];
  }
}

// ---------------- M[b,h,l] = max_s QK - sum_s QK / 4096 ----------------
__global__ __launch_bounds__(256) void m_kernel(const float* __restrict__ qt,
                                                const float* __restrict__ kt,
                                                const int* __restrict__ idx,
                                                float* __restrict__ M) {
  const int wave = threadIdx.x >> 6, lane = threadIdx.x & 63;
  const int gl = blockIdx.x * 4 + wave;       // 0..BH*L-1
  const int bh = gl >> 12, l = gl & (L_ - 1);
  const float* qtb = qt + (size_t)bh * L_ * D_;
  const float* ktb = kt + (size_t)bh * L_ * D_;
  const float qv = qtb[(size_t)l * D_ + lane];
  const int* ip = idx + l * U_PART;
  float mx = -INFINITY, sm = 0.0f;
#pragma unroll 5
  for (int s = 0; s < U_PART; s++) {
    int ki = ip[s];
    float p = qv * ktb[(size_t)ki * D_ + lane];
#pragma unroll
    for (int off = 32; off; off >>= 1) p += __shfl_xor(p, off, 64);
    mx = fmaxf(mx, p);
    sm += p;
  }
  if (lane == 0) M[gl] = mx - sm * (1.0f / 4096.0f);
}

// ---------------- top-45 indices per (b,h) ----------------
__global__ __launch_bounds__(256) void topk_kernel(const float* __restrict__ M,
                                                   int* __restrict__ mtop) {
  __shared__ float sv[L_];
  __shared__ float red_v[4];
  __shared__ int red_i[4];
  const int bh = blockIdx.x, t = threadIdx.x;
  const float* Mb = M + (size_t)bh * L_;
  for (int i = t; i < L_; i += 256) sv[i] = Mb[i];
  __syncthreads();
  for (int it = 0; it < TOPU; it++) {
    float bv = -INFINITY; int bi = 0x7fffffff;
    for (int i = t; i < L_; i += 256) {
      float v = sv[i];
      if (v > bv || (v == bv && i < bi)) { bv = v; bi = i; }
    }
#pragma unroll
    for (int off = 32; off; off >>= 1) {
      float ov = __shfl_xor(bv, off, 64);
      int   oi = __shfl_xor(bi, off, 64);
      if (ov > bv || (ov == bv && oi < bi)) { bv = ov; bi = oi; }
    }
    if ((t & 63) == 0) { red_v[t >> 6] = bv; red_i[t >> 6] = bi; }
    __syncthreads();
    if (t == 0) {
      for (int w = 1; w < 4; w++)
        if (red_v[w] > bv || (red_v[w] == bv && red_i[w] < bi)) { bv = red_v[w]; bi = red_i[w]; }
      mtop[bh * TOPU + it] = bi;
      sv[bi] = -INFINITY;
    }
    __syncthreads();
  }
}

// ---------------- out[bh,d,l] = cumsum_l v[bh,d,l] / 64 ----------------
__global__ __launch_bounds__(256) void cumsum_kernel(const float* __restrict__ v,
                                                     float* __restrict__ out) {
  const int row = blockIdx.x;                 // BH*D rows
  const float* src = v + (size_t)row * L_;
  float* dst = out + (size_t)row * L_;
  const int t = threadIdx.x;
  float vals[16];
  const float4* s4 = (const float4*)(src + t * 16);
#pragma unroll
  for (int i = 0; i < 4; i++) {
    float4 x = s4[i];
    vals[4 * i + 0] = x.x; vals[4 * i + 1] = x.y;
    vals[4 * i + 2] = x.z; vals[4 * i + 3] = x.w;
  }
  float run = 0.0f;
#pragma unroll
  for (int i = 0; i < 16; i++) { run += vals[i] * (1.0f / 64.0f); vals[i] = run; }
  float x = run;
#pragma unroll
  for (int off = 1; off < 64; off <<= 1) {
    float y = __shfl_up(x, off, 64);
    if ((t & 63) >= off) x += y;
  }
  __shared__ float wtot[4];
  if ((t & 63) == 63) wtot[t >> 6] = x;
  __syncthreads();
  float woff = 0.0f;
  for (int w = 0; w < (t >> 6); w++) woff += wtot[w];
  const float excl = x - run + woff;
#pragma unroll
  for (int i = 0; i < 16; i++) vals[i] += excl;
  float4* d4 = (float4*)(dst + t * 16);
#pragma unroll
  for (int i = 0; i < 4; i++)
    d4[i] = make_float4(vals[4 * i], vals[4 * i + 1], vals[4 * i + 2], vals[4 * i + 3]);
}

// ---------------- attention update, phase 1: per-(row,chunk) partials ----------------
// part[row][chunk] = { acc[64] (unnormalized exp*V), max, expsum }
__global__ __launch_bounds__(256) void update_partial(const float* __restrict__ qt,
                                                      const float* __restrict__ kt,
                                                      const float* __restrict__ vt,
                                                      const int* __restrict__ mtop,
                                                      float* __restrict__ part) {
  const int row = blockIdx.y;                 // 0..BH*TOPU-1
  const int ch = blockIdx.x;                  // 0..NCH-1
  const int bh = row / TOPU;
  const int sel = mtop[row];
  const int n = sel + 1;                      // causal length
  const int k0 = ch * CHUNK;
  float* p = part + ((size_t)row * NCH + ch) * PSTRIDE;
  const int t = threadIdx.x;

  if (k0 >= n) {                              // fully-masked chunk
    if (t < 64) p[t] = 0.0f;
    if (t == 64) p[64] = -INFINITY;
    if (t == 65) p[65] = 0.0f;
    return;
  }
  const int kn = min(n - k0, CHUNK);

  const float* qtb = qt + (size_t)bh * L_ * D_;
  const float* ktb = kt + ((size_t)bh * L_ + k0) * D_;
  const float* vtb = vt + ((size_t)bh * L_ + k0) * D_;

  __shared__ float qs[64];
  __shared__ float e[CHUNK];
  __shared__ float red[8];
  __shared__ float accs[4][64];
  if (t < 64) qs[t] = qtb[(size_t)sel * D_ + t];
  __syncthreads();

  float lmax = -INFINITY;
  for (int k = t; k < kn; k += 256) {
    const float4* kr = (const float4*)(ktb + (size_t)k * D_);
    float acc = 0.0f;
#pragma unroll
    for (int i = 0; i < 16; i++) {
      float4 kk = kr[i];
      acc += qs[4 * i] * kk.x + qs[4 * i + 1] * kk.y +
             qs[4 * i + 2] * kk.z + qs[4 * i + 3] * kk.w;
    }
    acc *= (1.0f / 512.0f);
    e[k] = acc;
    lmax = fmaxf(lmax, acc);
  }
#pragma unroll
  for (int off = 32; off; off >>= 1) lmax = fmaxf(lmax, __shfl_xor(lmax, off, 64));
  if ((t & 63) == 0) red[t >> 6] = lmax;
  __syncthreads();
  const float gmax = fmaxf(fmaxf(red[0], red[1]), fmaxf(red[2], red[3]));

  float lsum = 0.0f;
  for (int k = t; k < kn; k += 256) {
    float ex = expf(e[k] - gmax);
    e[k] = ex;
    lsum += ex;
  }
#pragma unroll
  for (int off = 32; off; off >>= 1) lsum += __shfl_xor(lsum, off, 64);
  __syncthreads();                            // e[] writes done before PV reads
  if ((t & 63) == 0) red[4 + (t >> 6)] = lsum;

  const int w = t >> 6, d = t & 63;
  float acc = 0.0f;
  for (int k = w; k < kn; k += 4) acc += e[k] * vtb[(size_t)k * D_ + d];
  accs[w][d] = acc;
  __syncthreads();
  if (t < 64) {
    p[t] = accs[0][t] + accs[1][t] + accs[2][t] + accs[3][t];
  } else if (t == 64) {
    p[64] = gmax;
  } else if (t == 65) {
    p[65] = red[4] + red[5] + red[6] + red[7];
  }
}

// ---------------- attention update, phase 2: combine + write column ----------------
__global__ __launch_bounds__(64) void update_combine(const float* __restrict__ part,
                                                     const int* __restrict__ mtop,
                                                     float* __restrict__ out) {
  const int row = blockIdx.x;                 // 0..BH*TOPU-1
  const int bh = row / TOPU;
  const int sel = mtop[row];
  const int d = threadIdx.x;                  // 0..63
  const float* p = part + (size_t)row * NCH * PSTRIDE;

  float m = -INFINITY;
#pragma unroll
  for (int c = 0; c < NCH; c++) m = fmaxf(m, p[c * PSTRIDE + 64]);

  float num = 0.0f, den = 0.0f;
#pragma unroll
  for (int c = 0; c < NCH; c++) {
    float mc = p[c * PSTRIDE + 64];
    if (mc > -INFINITY) {
      float wgt = expf(mc - m);
      num += wgt * p[c * PSTRIDE + d];
      den += wgt * p[c * PSTRIDE + 65];
    }
  }
  out[((size_t)bh * D_ + d) * L_ + sel] = num / den;
}

extern "C" void kernel_launch(void* const* d_in, const int* in_sizes, int n_in,
                              void* d_out, int out_size, void* d_ws, size_t ws_size,
                              hipStream_t stream) {
  const float* q = (const float*)d_in[0];
  const float* k = (const float*)d_in[1];
  const float* v = (const float*)d_in[2];
  float* out = (float*)d_out;

  const size_t NT = (size_t)BH * L_ * D_;     // 8388608 floats per tensor
  float* qt = (float*)d_ws;
  float* kt = qt + NT;
  float* vt = kt + NT;
  float* M  = vt + NT;                         // BH*L floats
  int* idx  = (int*)(M + (size_t)BH * L_);     // 4096*25 ints
  int* mtop = idx + L_ * U_PART;               // BH*45 ints
  float* part = (float*)(mtop + BH * TOPU);    // 1440*8*66 floats (~3 MB)

  uint32_t k2a, k2b;
#if JAX_THREEFRY_PARTITIONABLE
  tf2x32(0u, 42u, 0u, 1u, k2a, k2b);
#else
  uint32_t a0, a1, b0, b1;
  tf2x32(0u, 42u, 0u, 2u, a0, a1);
  tf2x32(0u, 42u, 1u, 3u, b0, b1);
  k2a = a1; k2b = b1;
#endif

  transpose_scale<<<dim3(L_ / 64, BH, 3), 256, 0, stream>>>(q, k, v, qt, kt, vt);
#if JAX_THREEFRY_PARTITIONABLE
  sample_idx_kernel<<<(L_ * U_PART + 255) / 256, 256, 0, stream>>>(idx, k2a, k2b);
#else
  sample_idx_kernel<<<(L_ * U_PART / 2 + 255) / 256, 256, 0, stream>>>(idx, k2a, k2b);
#endif
  m_kernel<<<BH * L_ / 4, 256, 0, stream>>>(qt, kt, idx, M);
  topk_kernel<<<BH, 256, 0, stream>>>(M, mtop);
  cumsum_kernel<<<BH * D_, 256, 0, stream>>>(v, out);
  update_partial<<<dim3(NCH, BH * TOPU), 256, 0, stream>>>(qt, kt, vt, mtop, part);
  update_combine<<<BH * TOPU, 64, 0, stream>>>(part, mtop, out);
}

// Round 3
// 589.510 us; speedup vs baseline: 1.4657x; 1.4491x over previous
//
#include <hip/hip_runtime.h>
#include <cstdint>

// Reference geometry (fixed problem)
constexpr int B_ = 4, H_ = 8, D_ = 64, L_ = 4096;
constexpr int BH = B_ * H_;          // 32
constexpr int U_PART = 25;           // FACTOR * ceil(log(64))
constexpr int TOPU = 45;             // FACTOR * ceil(log(4096))
constexpr int CHUNK = 512;           // keys per partial-update block
constexpr int NCH = L_ / CHUNK;      // 8 chunks
constexpr int PSTRIDE = 66;          // acc[64], max, sum

#define JAX_THREEFRY_PARTITIONABLE 1

// ---------------- Threefry-2x32 (exact JAX semantics) ----------------
__host__ __device__ inline void tf2x32(uint32_t k0, uint32_t k1,
                                       uint32_t x0, uint32_t x1,
                                       uint32_t& y0, uint32_t& y1) {
  const uint32_t ks2 = k0 ^ k1 ^ 0x1BD11BDAu;
  uint32_t v0 = x0 + k0, v1 = x1 + k1;
#define RND(r) { v0 += v1; v1 = (v1 << (r)) | (v1 >> (32 - (r))); v1 ^= v0; }
  RND(13) RND(15) RND(26) RND(6)
  v0 += k1; v1 += ks2 + 1u;
  RND(17) RND(29) RND(16) RND(24)
  v0 += ks2; v1 += k0 + 2u;
  RND(13) RND(15) RND(26) RND(6)
  v0 += k0; v1 += k1 + 3u;
  RND(17) RND(29) RND(16) RND(24)
  v0 += k1; v1 += ks2 + 4u;
  RND(13) RND(15) RND(26) RND(6)
  v0 += ks2; v1 += k0 + 5u;
#undef RND
  y0 = v0; y1 = v1;
}

__global__ __launch_bounds__(256) void sample_idx_kernel(int* __restrict__ idx,
                                                         uint32_t k2a, uint32_t k2b) {
#if JAX_THREEFRY_PARTITIONABLE
  int i = blockIdx.x * 256 + threadIdx.x;
  if (i >= L_ * U_PART) return;
  uint32_t y0, y1;
  tf2x32(k2a, k2b, 0u, (uint32_t)i, y0, y1);
  idx[i] = (int)((y0 ^ y1) & 4095u);
#else
  int j = blockIdx.x * 256 + threadIdx.x;
  const int half = (L_ * U_PART) / 2;   // 51200
  if (j >= half) return;
  uint32_t y0, y1;
  tf2x32(k2a, k2b, (uint32_t)j, (uint32_t)(j + half), y0, y1);
  idx[j] = (int)(y0 & 4095u);
  idx[j + half] = (int)(y1 & 4095u);
#endif
}

// ---------------- Transpose + scale: (BH, D, L) -> (BH, L, D) ----------------
__global__ __launch_bounds__(256) void transpose_scale(
    const float* __restrict__ q, const float* __restrict__ k, const float* __restrict__ v,
    float* __restrict__ qt, float* __restrict__ kt, float* __restrict__ vt) {
  const float* src; float* dst; float scale;
  if (blockIdx.z == 0)      { src = q; dst = qt; scale = 1.0f / 512.0f; }
  else if (blockIdx.z == 1) { src = k; dst = kt; scale = 1.0f / 64.0f; }
  else                      { src = v; dst = vt; scale = 1.0f / 64.0f; }
  const int bh = blockIdx.y;
  const int l0 = blockIdx.x * 64;
  __shared__ float tile[64][65];
  const float* s = src + (size_t)bh * D_ * L_;
  float* d = dst + (size_t)bh * L_ * D_;
  const int t = threadIdx.x;
#pragma unroll
  for (int i = 0; i < 16; i++) {
    int li = i * 256 + t;          // 0..4095
    int dd = li >> 6, ll = li & 63;
    tile[dd][ll] = s[(size_t)dd * L_ + l0 + ll] * scale;
  }
  __syncthreads();
#pragma unroll
  for (int i = 0; i < 16; i++) {
    int li = i * 256 + t;
    int ll = li >> 6, dd = li & 63;
    d[(size_t)(l0 + ll) * D_ + dd] = tile[dd][ll];
  }
}

// ---------------- M[b,h,l] = max_s QK - sum_s QK / 4096 ----------------
__global__ __launch_bounds__(256) void m_kernel(const float* __restrict__ qt,
                                                const float* __restrict__ kt,
                                                const int* __restrict__ idx,
                                                float* __restrict__ M) {
  const int wave = threadIdx.x >> 6, lane = threadIdx.x & 63;
  const int gl = blockIdx.x * 4 + wave;       // 0..BH*L-1
  const int bh = gl >> 12, l = gl & (L_ - 1);
  const float* qtb = qt + (size_t)bh * L_ * D_;
  const float* ktb = kt + (size_t)bh * L_ * D_;
  const float qv = qtb[(size_t)l * D_ + lane];
  const int* ip = idx + l * U_PART;
  float mx = -INFINITY, sm = 0.0f;
#pragma unroll 5
  for (int s = 0; s < U_PART; s++) {
    int ki = ip[s];
    float p = qv * ktb[(size_t)ki * D_ + lane];
#pragma unroll
    for (int off = 32; off; off >>= 1) p += __shfl_xor(p, off, 64);
    mx = fmaxf(mx, p);
    sm += p;
  }
  if (lane == 0) M[gl] = mx - sm * (1.0f / 4096.0f);
}

// ---------------- top-45 indices per (b,h) ----------------
__global__ __launch_bounds__(256) void topk_kernel(const float* __restrict__ M,
                                                   int* __restrict__ mtop) {
  __shared__ float sv[L_];
  __shared__ float red_v[4];
  __shared__ int red_i[4];
  const int bh = blockIdx.x, t = threadIdx.x;
  const float* Mb = M + (size_t)bh * L_;
  for (int i = t; i < L_; i += 256) sv[i] = Mb[i];
  __syncthreads();
  for (int it = 0; it < TOPU; it++) {
    float bv = -INFINITY; int bi = 0x7fffffff;
    for (int i = t; i < L_; i += 256) {
      float v = sv[i];
      if (v > bv || (v == bv && i < bi)) { bv = v; bi = i; }
    }
#pragma unroll
    for (int off = 32; off; off >>= 1) {
      float ov = __shfl_xor(bv, off, 64);
      int   oi = __shfl_xor(bi, off, 64);
      if (ov > bv || (ov == bv && oi < bi)) { bv = ov; bi = oi; }
    }
    if ((t & 63) == 0) { red_v[t >> 6] = bv; red_i[t >> 6] = bi; }
    __syncthreads();
    if (t == 0) {
      for (int w = 1; w < 4; w++)
        if (red_v[w] > bv || (red_v[w] == bv && red_i[w] < bi)) { bv = red_v[w]; bi = red_i[w]; }
      mtop[bh * TOPU + it] = bi;
      sv[bi] = -INFINITY;
    }
    __syncthreads();
  }
}

// ---------------- out[bh,d,l] = cumsum_l v[bh,d,l] / 64 ----------------
__global__ __launch_bounds__(256) void cumsum_kernel(const float* __restrict__ v,
                                                     float* __restrict__ out) {
  const int row = blockIdx.x;                 // BH*D rows
  const float* src = v + (size_t)row * L_;
  float* dst = out + (size_t)row * L_;
  const int t = threadIdx.x;
  float vals[16];
  const float4* s4 = (const float4*)(src + t * 16);
#pragma unroll
  for (int i = 0; i < 4; i++) {
    float4 x = s4[i];
    vals[4 * i + 0] = x.x; vals[4 * i + 1] = x.y;
    vals[4 * i + 2] = x.z; vals[4 * i + 3] = x.w;
  }
  float run = 0.0f;
#pragma unroll
  for (int i = 0; i < 16; i++) { run += vals[i] * (1.0f / 64.0f); vals[i] = run; }
  float x = run;
#pragma unroll
  for (int off = 1; off < 64; off <<= 1) {
    float y = __shfl_up(x, off, 64);
    if ((t & 63) >= off) x += y;
  }
  __shared__ float wtot[4];
  if ((t & 63) == 63) wtot[t >> 6] = x;
  __syncthreads();
  float woff = 0.0f;
  for (int w = 0; w < (t >> 6); w++) woff += wtot[w];
  const float excl = x - run + woff;
#pragma unroll
  for (int i = 0; i < 16; i++) vals[i] += excl;
  float4* d4 = (float4*)(dst + t * 16);
#pragma unroll
  for (int i = 0; i < 4; i++)
    d4[i] = make_float4(vals[4 * i], vals[4 * i + 1], vals[4 * i + 2], vals[4 * i + 3]);
}

// ---------------- attention update, phase 1: per-(row,chunk) partials ----------------
// QK uses RAW k in (D,L) layout -> coalesced (consecutive keys = consecutive lanes).
// Scales folded: qs = q/512, k raw; scores = qs.k_raw / 32768 (power-of-2, bit-exact).
__global__ __launch_bounds__(256) void update_partial(const float* __restrict__ qt,
                                                      const float* __restrict__ kraw,
                                                      const float* __restrict__ vt,
                                                      const int* __restrict__ mtop,
                                                      float* __restrict__ part) {
  const int row = blockIdx.y;                 // 0..BH*TOPU-1
  const int ch = blockIdx.x;                  // 0..NCH-1
  const int bh = row / TOPU;
  const int sel = mtop[row];
  const int n = sel + 1;                      // causal length
  const int k0 = ch * CHUNK;
  float* p = part + ((size_t)row * NCH + ch) * PSTRIDE;
  const int t = threadIdx.x;

  if (k0 >= n) {                              // fully-masked chunk
    if (t < 64) p[t] = 0.0f;
    if (t == 64) p[64] = -INFINITY;
    if (t == 65) p[65] = 0.0f;
    return;
  }
  const int kn = min(n - k0, CHUNK);

  __shared__ float qs[64];
  __shared__ float e[CHUNK];
  __shared__ float red[8];
  __shared__ float accs[4][64];
  if (t < 64) qs[t] = qt[((size_t)bh * L_ + sel) * D_ + t];
  __syncthreads();

  // ---- QK: thread t owns key rows (k0+2t, k0+2t+1); loads coalesced over t ----
  const float* kb = kraw + (size_t)bh * D_ * L_ + k0 + 2 * t;
  float a0 = 0.0f, a1 = 0.0f;
#pragma unroll 8
  for (int d = 0; d < D_; d++) {
    float qd = qs[d];
    float2 kk = *(const float2*)(kb + (size_t)d * L_);
    a0 += qd * kk.x;
    a1 += qd * kk.y;
  }
  a0 *= (1.0f / 32768.0f);
  a1 *= (1.0f / 32768.0f);

  float lmax = -INFINITY;
  if (2 * t < kn)     { e[2 * t] = a0; lmax = a0; }
  if (2 * t + 1 < kn) { e[2 * t + 1] = a1; lmax = fmaxf(lmax, a1); }
#pragma unroll
  for (int off = 32; off; off >>= 1) lmax = fmaxf(lmax, __shfl_xor(lmax, off, 64));
  if ((t & 63) == 0) red[t >> 6] = lmax;
  __syncthreads();
  const float gmax = fmaxf(fmaxf(red[0], red[1]), fmaxf(red[2], red[3]));

  float lsum = 0.0f;
  for (int k = t; k < kn; k += 256) {
    float ex = expf(e[k] - gmax);
    e[k] = ex;
    lsum += ex;
  }
#pragma unroll
  for (int off = 32; off; off >>= 1) lsum += __shfl_xor(lsum, off, 64);
  __syncthreads();                            // e[] writes done before PV reads
  if ((t & 63) == 0) red[4 + (t >> 6)] = lsum;

  // ---- PV: wave w, lane d; vt rows are coalesced over d ----
  const float* vtb = vt + ((size_t)bh * L_ + k0) * D_;
  const int w = t >> 6, d = t & 63;
  float acc = 0.0f;
  for (int k = w; k < kn; k += 4) acc += e[k] * vtb[(size_t)k * D_ + d];
  accs[w][d] = acc;
  __syncthreads();
  if (t < 64) {
    p[t] = accs[0][t] + accs[1][t] + accs[2][t] + accs[3][t];
  } else if (t == 64) {
    p[64] = gmax;
  } else if (t == 65) {
    p[65] = red[4] + red[5] + red[6] + red[7];
  }
}

// ---------------- attention update, phase 2: combine + write column ----------------
__global__ __launch_bounds__(64) void update_combine(const float* __restrict__ part,
                                                     const int* __restrict__ mtop,
                                                     float* __restrict__ out) {
  const int row = blockIdx.x;                 // 0..BH*TOPU-1
  const int bh = row / TOPU;
  const int sel = mtop[row];
  const int d = threadIdx.x;                  // 0..63
  const float* p = part + (size_t)row * NCH * PSTRIDE;

  float m = -INFINITY;
#pragma unroll
  for (int c = 0; c < NCH; c++) m = fmaxf(m, p[c * PSTRIDE + 64]);

  float num = 0.0f, den = 0.0f;
#pragma unroll
  for (int c = 0; c < NCH; c++) {
    float mc = p[c * PSTRIDE + 64];
    if (mc > -INFINITY) {
      float wgt = expf(mc - m);
      num += wgt * p[c * PSTRIDE + d];
      den += wgt * p[c * PSTRIDE + 65];
    }
  }
  out[((size_t)bh * D_ + d) * L_ + sel] = num / den;
}

extern "C" void kernel_launch(void* const* d_in, const int* in_sizes, int n_in,
                              void* d_out, int out_size, void* d_ws, size_t ws_size,
                              hipStream_t stream) {
  const float* q = (const float*)d_in[0];
  const float* k = (const float*)d_in[1];
  const float* v = (const float*)d_in[2];
  float* out = (float*)d_out;

  const size_t NT = (size_t)BH * L_ * D_;     // 8388608 floats per tensor
  float* qt = (float*)d_ws;
  float* kt = qt + NT;
  float* vt = kt + NT;
  float* M  = vt + NT;                         // BH*L floats
  int* idx  = (int*)(M + (size_t)BH * L_);     // 4096*25 ints
  int* mtop = idx + L_ * U_PART;               // BH*45 ints
  float* part = (float*)(mtop + BH * TOPU);    // 1440*8*66 floats (~3 MB)

  uint32_t k2a, k2b;
#if JAX_THREEFRY_PARTITIONABLE
  tf2x32(0u, 42u, 0u, 1u, k2a, k2b);
#else
  uint32_t a0, a1, b0, b1;
  tf2x32(0u, 42u, 0u, 2u, a0, a1);
  tf2x32(0u, 42u, 1u, 3u, b0, b1);
  k2a = a1; k2b = b1;
#endif

  transpose_scale<<<dim3(L_ / 64, BH, 3), 256, 0, stream>>>(q, k, v, qt, kt, vt);
#if JAX_THREEFRY_PARTITIONABLE
  sample_idx_kernel<<<(L_ * U_PART + 255) / 256, 256, 0, stream>>>(idx, k2a, k2b);
#else
  sample_idx_kernel<<<(L_ * U_PART / 2 + 255) / 256, 256, 0, stream>>>(idx, k2a, k2b);
#endif
  m_kernel<<<BH * L_ / 4, 256, 0, stream>>>(qt, kt, idx, M);
  topk_kernel<<<BH, 256, 0, stream>>>(M, mtop);
  cumsum_kernel<<<BH * D_, 256, 0, stream>>>(v, out);
  update_partial<<<dim3(NCH, BH * TOPU), 256, 0, stream>>>(qt, k, vt, mtop, part);
  update_combine<<<BH * TOPU, 64, 0, stream>>>(part, mtop, out);
}

// Round 4
// 379.306 us; speedup vs baseline: 2.2780x; 1.5542x over previous
//
#include <hip/hip_runtime.h>
#include <cstdint>

// Reference geometry (fixed problem)
constexpr int B_ = 4, H_ = 8, D_ = 64, L_ = 4096;
constexpr int BH = B_ * H_;          // 32
constexpr int U_PART = 25;           // FACTOR * ceil(log(64))
constexpr int TOPU = 45;             // FACTOR * ceil(log(4096))
constexpr int CHUNK = 128;           // keys per update chunk (LDS-staged)
constexpr int NCH = L_ / CHUNK;      // 32 chunks
constexpr int PSTRIDE = 66;          // acc[64], max, sum

#define JAX_THREEFRY_PARTITIONABLE 1

// ---------------- Threefry-2x32 (exact JAX semantics) ----------------
__host__ __device__ inline void tf2x32(uint32_t k0, uint32_t k1,
                                       uint32_t x0, uint32_t x1,
                                       uint32_t& y0, uint32_t& y1) {
  const uint32_t ks2 = k0 ^ k1 ^ 0x1BD11BDAu;
  uint32_t v0 = x0 + k0, v1 = x1 + k1;
#define RND(r) { v0 += v1; v1 = (v1 << (r)) | (v1 >> (32 - (r))); v1 ^= v0; }
  RND(13) RND(15) RND(26) RND(6)
  v0 += k1; v1 += ks2 + 1u;
  RND(17) RND(29) RND(16) RND(24)
  v0 += ks2; v1 += k0 + 2u;
  RND(13) RND(15) RND(26) RND(6)
  v0 += k0; v1 += k1 + 3u;
  RND(17) RND(29) RND(16) RND(24)
  v0 += k1; v1 += ks2 + 4u;
  RND(13) RND(15) RND(26) RND(6)
  v0 += ks2; v1 += k0 + 5u;
#undef RND
  y0 = v0; y1 = v1;
}

__global__ __launch_bounds__(256) void sample_idx_kernel(int* __restrict__ idx,
                                                         uint32_t k2a, uint32_t k2b) {
#if JAX_THREEFRY_PARTITIONABLE
  int i = blockIdx.x * 256 + threadIdx.x;
  if (i >= L_ * U_PART) return;
  uint32_t y0, y1;
  tf2x32(k2a, k2b, 0u, (uint32_t)i, y0, y1);
  idx[i] = (int)((y0 ^ y1) & 4095u);
#else
  int j = blockIdx.x * 256 + threadIdx.x;
  const int half = (L_ * U_PART) / 2;   // 51200
  if (j >= half) return;
  uint32_t y0, y1;
  tf2x32(k2a, k2b, (uint32_t)j, (uint32_t)(j + half), y0, y1);
  idx[j] = (int)(y0 & 4095u);
  idx[j + half] = (int)(y1 & 4095u);
#endif
}

// ---------------- Transpose + scale: (BH, D, L) -> (BH, L, D) ----------------
__global__ __launch_bounds__(256) void transpose_scale(
    const float* __restrict__ q, const float* __restrict__ k, const float* __restrict__ v,
    float* __restrict__ qt, float* __restrict__ kt, float* __restrict__ vt) {
  const float* src; float* dst; float scale;
  if (blockIdx.z == 0)      { src = q; dst = qt; scale = 1.0f / 512.0f; }
  else if (blockIdx.z == 1) { src = k; dst = kt; scale = 1.0f / 64.0f; }
  else                      { src = v; dst = vt; scale = 1.0f / 64.0f; }
  const int bh = blockIdx.y;
  const int l0 = blockIdx.x * 64;
  __shared__ float tile[64][65];
  const float* s = src + (size_t)bh * D_ * L_;
  float* d = dst + (size_t)bh * L_ * D_;
  const int t = threadIdx.x;
#pragma unroll
  for (int i = 0; i < 16; i++) {
    int li = i * 256 + t;          // 0..4095
    int dd = li >> 6, ll = li & 63;
    tile[dd][ll] = s[(size_t)dd * L_ + l0 + ll] * scale;
  }
  __syncthreads();
#pragma unroll
  for (int i = 0; i < 16; i++) {
    int li = i * 256 + t;
    int ll = li >> 6, dd = li & 63;
    d[(size_t)(l0 + ll) * D_ + dd] = tile[dd][ll];
  }
}

// ---------------- M[b,h,l] = max_s QK - sum_s QK / 4096 ----------------
// 16 lanes per l (float4 fragments), 4 l per wave, 16 l per block.
__global__ __launch_bounds__(256) void m_kernel(const float* __restrict__ qt,
                                                const float* __restrict__ kt,
                                                const int* __restrict__ idx,
                                                float* __restrict__ M) {
  const int t = threadIdx.x;
  const int w = t >> 6, lane = t & 63;
  const int g = lane >> 4, gl = lane & 15;     // group in wave, lane in group
  const int gidx = blockIdx.x * 16 + w * 4 + g;   // 0..BH*L-1
  const int bh = gidx >> 12, l = gidx & (L_ - 1);
  const float* qtb = qt + (size_t)bh * L_ * D_;
  const float* ktb = kt + (size_t)bh * L_ * D_;
  const float4 ql = *(const float4*)(qtb + (size_t)l * D_ + gl * 4);
  const int* ip = idx + l * U_PART;
  float mx = -INFINITY, sm = 0.0f;
#pragma unroll 5
  for (int s = 0; s < U_PART; s++) {
    int ki = ip[s];
    float4 kk = *(const float4*)(ktb + (size_t)ki * D_ + gl * 4);
    float p = ql.x * kk.x + ql.y * kk.y + ql.z * kk.z + ql.w * kk.w;
    p += __shfl_xor(p, 8, 64);
    p += __shfl_xor(p, 4, 64);
    p += __shfl_xor(p, 2, 64);
    p += __shfl_xor(p, 1, 64);
    mx = fmaxf(mx, p);
    sm += p;
  }
  if (gl == 0) M[gidx] = mx - sm * (1.0f / 4096.0f);
}

// ---------------- top-45 indices per (b,h) ----------------
__global__ __launch_bounds__(256) void topk_kernel(const float* __restrict__ M,
                                                   int* __restrict__ mtop) {
  __shared__ float sv[L_];
  __shared__ float red_v[4];
  __shared__ int red_i[4];
  const int bh = blockIdx.x, t = threadIdx.x;
  const float* Mb = M + (size_t)bh * L_;
  for (int i = t; i < L_; i += 256) sv[i] = Mb[i];
  __syncthreads();
  for (int it = 0; it < TOPU; it++) {
    float bv = -INFINITY; int bi = 0x7fffffff;
    for (int i = t; i < L_; i += 256) {
      float v = sv[i];
      if (v > bv || (v == bv && i < bi)) { bv = v; bi = i; }
    }
#pragma unroll
    for (int off = 32; off; off >>= 1) {
      float ov = __shfl_xor(bv, off, 64);
      int   oi = __shfl_xor(bi, off, 64);
      if (ov > bv || (ov == bv && oi < bi)) { bv = ov; bi = oi; }
    }
    if ((t & 63) == 0) { red_v[t >> 6] = bv; red_i[t >> 6] = bi; }
    __syncthreads();
    if (t == 0) {
      for (int ww = 1; ww < 4; ww++)
        if (red_v[ww] > bv || (red_v[ww] == bv && red_i[ww] < bi)) { bv = red_v[ww]; bi = red_i[ww]; }
      mtop[bh * TOPU + it] = bi;
      sv[bi] = -INFINITY;
    }
    __syncthreads();
  }
}

// ---------------- out[bh,d,l] = cumsum_l v[bh,d,l] / 64 ----------------
__global__ __launch_bounds__(256) void cumsum_kernel(const float* __restrict__ v,
                                                     float* __restrict__ out) {
  const int row = blockIdx.x;                 // BH*D rows
  const float* src = v + (size_t)row * L_;
  float* dst = out + (size_t)row * L_;
  const int t = threadIdx.x;
  float vals[16];
  const float4* s4 = (const float4*)(src + t * 16);
#pragma unroll
  for (int i = 0; i < 4; i++) {
    float4 x = s4[i];
    vals[4 * i + 0] = x.x; vals[4 * i + 1] = x.y;
    vals[4 * i + 2] = x.z; vals[4 * i + 3] = x.w;
  }
  float run = 0.0f;
#pragma unroll
  for (int i = 0; i < 16; i++) { run += vals[i] * (1.0f / 64.0f); vals[i] = run; }
  float x = run;
#pragma unroll
  for (int off = 1; off < 64; off <<= 1) {
    float y = __shfl_up(x, off, 64);
    if ((t & 63) >= off) x += y;
  }
  __shared__ float wtot[4];
  if ((t & 63) == 63) wtot[t >> 6] = x;
  __syncthreads();
  float woff = 0.0f;
  for (int w = 0; w < (t >> 6); w++) woff += wtot[w];
  const float excl = x - run + woff;
#pragma unroll
  for (int i = 0; i < 16; i++) vals[i] += excl;
  float4* d4 = (float4*)(dst + t * 16);
#pragma unroll
  for (int i = 0; i < 4; i++)
    d4[i] = make_float4(vals[4 * i], vals[4 * i + 1], vals[4 * i + 2], vals[4 * i + 3]);
}

// ---------------- update phase 1: block per (bh, chunk), LDS-staged K/V ----------------
// kS[d][key] (then overwritten by vS[key][d]); all 45 rows reuse the staged chunk.
// Wave w handles rows w, w+4, w+8, ...; scores live in registers across phases.
__global__ __launch_bounds__(256) void update_partial(const float* __restrict__ qt,
                                                      const float* __restrict__ kraw,
                                                      const float* __restrict__ vt,
                                                      const int* __restrict__ mtop,
                                                      float* __restrict__ part) {
  const int ch = blockIdx.x;                  // 0..NCH-1
  const int bh = blockIdx.y;                  // 0..BH-1
  const int k0 = ch * CHUNK;
  const int t = threadIdx.x;
  const int w = t >> 6, lane = t & 63;

  __shared__ float buf[D_ * CHUNK];           // 32 KB: kS then vS
  __shared__ int sels[TOPU];
  if (t < TOPU) sels[t] = mtop[bh * TOPU + t];

  // stage K: buf[d*128 + key] = kraw[bh, d, k0+key]  (coalesced, conflict-free)
  const float* kb = kraw + (size_t)bh * D_ * L_;
#pragma unroll
  for (int j = 0; j < 8; j++) {
    int e4 = 4 * (t + 256 * j);
    int d = e4 >> 7, key = e4 & 127;
    *(float4*)&buf[e4] = *(const float4*)&kb[(size_t)d * L_ + k0 + key];
  }
  __syncthreads();

  float elo[12], ehi[12];                     // exp weights, 2 keys/lane/row
#pragma unroll
  for (int i = 0; i < 12; i++) {
    const int r = w + i * 4;
    elo[i] = 0.0f; ehi[i] = 0.0f;
    if (r >= TOPU) continue;
    const int sel = sels[r];
    if (k0 > sel) continue;                   // chunk fully masked for this row
    // q row: lane d holds qt[bh, sel, d]
    const float qreg = qt[((size_t)bh * L_ + sel) * D_ + lane];
    float s0 = 0.0f, s1 = 0.0f;
#pragma unroll 16
    for (int d = 0; d < D_; d++) {
      float qd = __shfl(qreg, d, 64);
      s0 += qd * buf[d * CHUNK + lane];
      s1 += qd * buf[d * CHUNK + 64 + lane];
    }
    s0 *= (1.0f / 32768.0f);                  // -> raw_dot / 2^24, == reference
    s1 *= (1.0f / 32768.0f);
    const int kg0 = k0 + lane, kg1 = k0 + 64 + lane;
    if (kg0 > sel) s0 = -INFINITY;            // causal mask
    if (kg1 > sel) s1 = -INFINITY;
    float mx = fmaxf(s0, s1);
#pragma unroll
    for (int off = 32; off; off >>= 1) mx = fmaxf(mx, __shfl_xor(mx, off, 64));
    float e0 = expf(s0 - mx);                 // exp(-inf)=0 handles mask
    float e1 = expf(s1 - mx);
    float sm = e0 + e1;
#pragma unroll
    for (int off = 32; off; off >>= 1) sm += __shfl_xor(sm, off, 64);
    elo[i] = e0; ehi[i] = e1;
    float* p = part + ((size_t)(bh * TOPU + r) * NCH + ch) * PSTRIDE;
    if (lane == 0) { p[64] = mx; p[65] = sm; }
  }
  __syncthreads();

  // stage V: buf[key*64 + d] = vt[bh, k0+key, d]  (linear copy)
  const float* vb = vt + ((size_t)bh * L_ + k0) * D_;
#pragma unroll
  for (int j = 0; j < 8; j++) {
    int e4 = 4 * (t + 256 * j);
    *(float4*)&buf[e4] = *(const float4*)&vb[e4];
  }
  __syncthreads();

  // PV: lane = d; exp weights broadcast from registers
#pragma unroll
  for (int i = 0; i < 12; i++) {
    const int r = w + i * 4;
    if (r >= TOPU) continue;
    const int sel = sels[r];
    if (k0 > sel) continue;
    float acc = 0.0f;
#pragma unroll 8
    for (int key = 0; key < 64; key++) {
      float ea = __shfl(elo[i], key, 64);
      float eb = __shfl(ehi[i], key, 64);
      acc += ea * buf[key * D_ + lane];
      acc += eb * buf[(key + 64) * D_ + lane];
    }
    float* p = part + ((size_t)(bh * TOPU + r) * NCH + ch) * PSTRIDE;
    p[lane] = acc;
  }
}

// ---------------- update phase 2: combine valid chunks + write column ----------------
__global__ __launch_bounds__(64) void update_combine(const float* __restrict__ part,
                                                     const int* __restrict__ mtop,
                                                     float* __restrict__ out) {
  const int row = blockIdx.x;                 // 0..BH*TOPU-1
  const int bh = row / TOPU;
  const int sel = mtop[row];
  const int d = threadIdx.x;                  // 0..63
  const int nv = sel / CHUNK + 1;             // valid chunks
  const float* p = part + (size_t)row * NCH * PSTRIDE;

  float m = -INFINITY;
  for (int c = 0; c < nv; c++) m = fmaxf(m, p[c * PSTRIDE + 64]);

  float num = 0.0f, den = 0.0f;
  for (int c = 0; c < nv; c++) {
    float mc = p[c * PSTRIDE + 64];
    float wgt = expf(mc - m);
    num += wgt * p[c * PSTRIDE + d];
    den += wgt * p[c * PSTRIDE + 65];
  }
  out[((size_t)bh * D_ + d) * L_ + sel] = num / den;
}

extern "C" void kernel_launch(void* const* d_in, const int* in_sizes, int n_in,
                              void* d_out, int out_size, void* d_ws, size_t ws_size,
                              hipStream_t stream) {
  const float* q = (const float*)d_in[0];
  const float* k = (const float*)d_in[1];
  const float* v = (const float*)d_in[2];
  float* out = (float*)d_out;

  const size_t NT = (size_t)BH * L_ * D_;     // 8388608 floats per tensor
  float* qt = (float*)d_ws;
  float* kt = qt + NT;
  float* vt = kt + NT;
  float* M  = vt + NT;                         // BH*L floats
  int* idx  = (int*)(M + (size_t)BH * L_);     // 4096*25 ints
  int* mtop = idx + L_ * U_PART;               // BH*45 ints
  float* part = (float*)(mtop + BH * TOPU);    // 1440*32*66 floats (~12 MB)

  uint32_t k2a, k2b;
#if JAX_THREEFRY_PARTITIONABLE
  tf2x32(0u, 42u, 0u, 1u, k2a, k2b);
#else
  uint32_t a0, a1, b0, b1;
  tf2x32(0u, 42u, 0u, 2u, a0, a1);
  tf2x32(0u, 42u, 1u, 3u, b0, b1);
  k2a = a1; k2b = b1;
#endif

  transpose_scale<<<dim3(L_ / 64, BH, 3), 256, 0, stream>>>(q, k, v, qt, kt, vt);
#if JAX_THREEFRY_PARTITIONABLE
  sample_idx_kernel<<<(L_ * U_PART + 255) / 256, 256, 0, stream>>>(idx, k2a, k2b);
#else
  sample_idx_kernel<<<(L_ * U_PART / 2 + 255) / 256, 256, 0, stream>>>(idx, k2a, k2b);
#endif
  m_kernel<<<BH * L_ / 16, 256, 0, stream>>>(qt, kt, idx, M);
  topk_kernel<<<BH, 256, 0, stream>>>(M, mtop);
  cumsum_kernel<<<BH * D_, 256, 0, stream>>>(v, out);
  update_partial<<<dim3(NCH, BH), 256, 0, stream>>>(qt, k, vt, mtop, part);
  update_combine<<<BH * TOPU, 64, 0, stream>>>(part, mtop, out);
}

// Round 5
// 273.259 us; speedup vs baseline: 3.1621x; 1.3881x over previous
//
#include <hip/hip_runtime.h>
#include <cstdint>

// Reference geometry (fixed problem)
constexpr int B_ = 4, H_ = 8, D_ = 64, L_ = 4096;
constexpr int BH = B_ * H_;          // 32
constexpr int U_PART = 25;           // FACTOR * ceil(log(64))
constexpr int TOPU = 45;             // FACTOR * ceil(log(4096))
constexpr int CHUNK = 128;           // keys per update chunk (LDS-staged)
constexpr int NCH = L_ / CHUNK;      // 32 chunks
constexpr int PSTRIDE = 68;          // acc[64], max, sum, pad to 16B-aligned stride

#define JAX_THREEFRY_PARTITIONABLE 1

// ---------------- Threefry-2x32 (exact JAX semantics) ----------------
__host__ __device__ inline void tf2x32(uint32_t k0, uint32_t k1,
                                       uint32_t x0, uint32_t x1,
                                       uint32_t& y0, uint32_t& y1) {
  const uint32_t ks2 = k0 ^ k1 ^ 0x1BD11BDAu;
  uint32_t v0 = x0 + k0, v1 = x1 + k1;
#define RND(r) { v0 += v1; v1 = (v1 << (r)) | (v1 >> (32 - (r))); v1 ^= v0; }
  RND(13) RND(15) RND(26) RND(6)
  v0 += k1; v1 += ks2 + 1u;
  RND(17) RND(29) RND(16) RND(24)
  v0 += ks2; v1 += k0 + 2u;
  RND(13) RND(15) RND(26) RND(6)
  v0 += k0; v1 += k1 + 3u;
  RND(17) RND(29) RND(16) RND(24)
  v0 += k1; v1 += ks2 + 4u;
  RND(13) RND(15) RND(26) RND(6)
  v0 += ks2; v1 += k0 + 5u;
#undef RND
  y0 = v0; y1 = v1;
}

__global__ __launch_bounds__(256) void sample_idx_kernel(int* __restrict__ idx,
                                                         uint32_t k2a, uint32_t k2b) {
#if JAX_THREEFRY_PARTITIONABLE
  int i = blockIdx.x * 256 + threadIdx.x;
  if (i >= L_ * U_PART) return;
  uint32_t y0, y1;
  tf2x32(k2a, k2b, 0u, (uint32_t)i, y0, y1);
  idx[i] = (int)((y0 ^ y1) & 4095u);
#else
  int j = blockIdx.x * 256 + threadIdx.x;
  const int half = (L_ * U_PART) / 2;   // 51200
  if (j >= half) return;
  uint32_t y0, y1;
  tf2x32(k2a, k2b, (uint32_t)j, (uint32_t)(j + half), y0, y1);
  idx[j] = (int)(y0 & 4095u);
  idx[j + half] = (int)(y1 & 4095u);
#endif
}

// ---------------- Transpose + scale: (BH, D, L) -> (BH, L, D) ----------------
__global__ __launch_bounds__(256) void transpose_scale(
    const float* __restrict__ q, const float* __restrict__ k, const float* __restrict__ v,
    float* __restrict__ qt, float* __restrict__ kt, float* __restrict__ vt) {
  const float* src; float* dst; float scale;
  if (blockIdx.z == 0)      { src = q; dst = qt; scale = 1.0f / 512.0f; }
  else if (blockIdx.z == 1) { src = k; dst = kt; scale = 1.0f / 64.0f; }
  else                      { src = v; dst = vt; scale = 1.0f / 64.0f; }
  const int bh = blockIdx.y;
  const int l0 = blockIdx.x * 64;
  __shared__ float tile[64][65];
  const float* s = src + (size_t)bh * D_ * L_;
  float* d = dst + (size_t)bh * L_ * D_;
  const int t = threadIdx.x;
#pragma unroll
  for (int i = 0; i < 16; i++) {
    int li = i * 256 + t;          // 0..4095
    int dd = li >> 6, ll = li & 63;
    tile[dd][ll] = s[(size_t)dd * L_ + l0 + ll] * scale;
  }
  __syncthreads();
#pragma unroll
  for (int i = 0; i < 16; i++) {
    int li = i * 256 + t;
    int ll = li >> 6, dd = li & 63;
    d[(size_t)(l0 + ll) * D_ + dd] = tile[dd][ll];
  }
}

// ---------------- M[b,h,l] = max_s QK - sum_s QK / 4096 ----------------
// 16 lanes per l (float4 fragments), 4 l per wave, 16 l per block.
__global__ __launch_bounds__(256) void m_kernel(const float* __restrict__ qt,
                                                const float* __restrict__ kt,
                                                const int* __restrict__ idx,
                                                float* __restrict__ M) {
  const int t = threadIdx.x;
  const int w = t >> 6, lane = t & 63;
  const int g = lane >> 4, gl = lane & 15;     // group in wave, lane in group
  const int gidx = blockIdx.x * 16 + w * 4 + g;   // 0..BH*L-1
  const int bh = gidx >> 12, l = gidx & (L_ - 1);
  const float* qtb = qt + (size_t)bh * L_ * D_;
  const float* ktb = kt + (size_t)bh * L_ * D_;
  const float4 ql = *(const float4*)(qtb + (size_t)l * D_ + gl * 4);
  const int* ip = idx + l * U_PART;
  float mx = -INFINITY, sm = 0.0f;
#pragma unroll 5
  for (int s = 0; s < U_PART; s++) {
    int ki = ip[s];
    float4 kk = *(const float4*)(ktb + (size_t)ki * D_ + gl * 4);
    float p = ql.x * kk.x + ql.y * kk.y + ql.z * kk.z + ql.w * kk.w;
    p += __shfl_xor(p, 8, 64);
    p += __shfl_xor(p, 4, 64);
    p += __shfl_xor(p, 2, 64);
    p += __shfl_xor(p, 1, 64);
    mx = fmaxf(mx, p);
    sm += p;
  }
  if (gl == 0) M[gidx] = mx - sm * (1.0f / 4096.0f);
}

// ---------------- top-45 per (b,h), emitted SORTED DESCENDING by index ----------------
__global__ __launch_bounds__(256) void topk_kernel(const float* __restrict__ M,
                                                   int* __restrict__ ssel_g) {
  __shared__ float sv[L_];
  __shared__ float red_v[4];
  __shared__ int red_i[4];
  __shared__ int picks[TOPU];
  const int bh = blockIdx.x, t = threadIdx.x;
  const float* Mb = M + (size_t)bh * L_;
  for (int i = t; i < L_; i += 256) sv[i] = Mb[i];
  __syncthreads();
  for (int it = 0; it < TOPU; it++) {
    float bv = -INFINITY; int bi = 0x7fffffff;
    for (int i = t; i < L_; i += 256) {
      float v = sv[i];
      if (v > bv || (v == bv && i < bi)) { bv = v; bi = i; }
    }
#pragma unroll
    for (int off = 32; off; off >>= 1) {
      float ov = __shfl_xor(bv, off, 64);
      int   oi = __shfl_xor(bi, off, 64);
      if (ov > bv || (ov == bv && oi < bi)) { bv = ov; bi = oi; }
    }
    if ((t & 63) == 0) { red_v[t >> 6] = bv; red_i[t >> 6] = bi; }
    __syncthreads();
    if (t == 0) {
      for (int ww = 1; ww < 4; ww++)
        if (red_v[ww] > bv || (red_v[ww] == bv && red_i[ww] < bi)) { bv = red_v[ww]; bi = red_i[ww]; }
      picks[it] = bi;
      sv[bi] = -INFINITY;
    }
    __syncthreads();
  }
  // rank-sort descending by key index (indices are distinct)
  if (t < TOPU) {
    int my = picks[t];
    int rank = 0;
    for (int j = 0; j < TOPU; j++) rank += (picks[j] > my);
    ssel_g[bh * TOPU + rank] = my;
  }
}

// ---------------- out[bh,d,l] = cumsum_l v[bh,d,l] / 64 ----------------
__global__ __launch_bounds__(256) void cumsum_kernel(const float* __restrict__ v,
                                                     float* __restrict__ out) {
  const int row = blockIdx.x;                 // BH*D rows
  const float* src = v + (size_t)row * L_;
  float* dst = out + (size_t)row * L_;
  const int t = threadIdx.x;
  float vals[16];
  const float4* s4 = (const float4*)(src + t * 16);
#pragma unroll
  for (int i = 0; i < 4; i++) {
    float4 x = s4[i];
    vals[4 * i + 0] = x.x; vals[4 * i + 1] = x.y;
    vals[4 * i + 2] = x.z; vals[4 * i + 3] = x.w;
  }
  float run = 0.0f;
#pragma unroll
  for (int i = 0; i < 16; i++) { run += vals[i] * (1.0f / 64.0f); vals[i] = run; }
  float x = run;
#pragma unroll
  for (int off = 1; off < 64; off <<= 1) {
    float y = __shfl_up(x, off, 64);
    if ((t & 63) >= off) x += y;
  }
  __shared__ float wtot[4];
  if ((t & 63) == 63) wtot[t >> 6] = x;
  __syncthreads();
  float woff = 0.0f;
  for (int w = 0; w < (t >> 6); w++) woff += wtot[w];
  const float excl = x - run + woff;
#pragma unroll
  for (int i = 0; i < 16; i++) vals[i] += excl;
  float4* d4 = (float4*)(dst + t * 16);
#pragma unroll
  for (int i = 0; i < 4; i++)
    d4[i] = make_float4(vals[4 * i], vals[4 * i + 1], vals[4 * i + 2], vals[4 * i + 3]);
}

// ---------------- update phase 1: register-tiled GEMM per (bh, chunk-pair) ----------------
// Block handles chunks {ch0, 31-ch0} (constant total work). Rows sorted desc by sel ->
// active rows per chunk are a prefix of length nact. Thread tiles: QK 3rows x 8keys,
// PV 3rows x 4d. All LDS strides padded for conflict-free access.
__global__ __launch_bounds__(256) void update_partial(const float* __restrict__ qt,
                                                      const float* __restrict__ kraw,
                                                      const float* __restrict__ vt,
                                                      const int* __restrict__ ssel_g,
                                                      float* __restrict__ part) {
  const int bidx = blockIdx.x;        // 0..511
  const int bh = bidx >> 4;
  const int ch0 = bidx & 15;
  const int t = threadIdx.x;
  const int w = t >> 6, lane = t & 63;
  const int kl = lane & 15, rg = lane >> 4;

  __shared__ float kv[CHUNK * 64];    // 32KB: kS[d][128] then vS[key][64]
  __shared__ float qs[48 * 68];       // padded stride 68 (16B-aligned, bank-spread)
  __shared__ float eS[48 * 132];      // padded stride 132
  __shared__ int ssel[48];

  if (t < 48) ssel[t] = (t < TOPU) ? ssel_g[bh * TOPU + t] : -1;
  __syncthreads();

  // stage Q: 48 rows x 64 d (rows 45..47 zero)
#pragma unroll
  for (int j = 0; j < 3; j++) {
    int it = t + 256 * j;             // 0..767
    int rr = it >> 4, dc = it & 15;
    int sel = ssel[rr];
    float4 qv = make_float4(0.f, 0.f, 0.f, 0.f);
    if (sel >= 0) qv = *(const float4*)&qt[((size_t)bh * L_ + sel) * D_ + 4 * dc];
    *(float4*)&qs[rr * 68 + 4 * dc] = qv;
  }

  for (int pass = 0; pass < 2; pass++) {
    const int ch = pass ? (31 - ch0) : ch0;
    const int k0 = ch * CHUNK;
    // nact = #rows with sel >= k0 (ssel descending): binary search
    int lo = 0, hi = TOPU;
    while (lo < hi) { int mid = (lo + hi) >> 1; if (ssel[mid] >= k0) lo = mid + 1; else hi = mid; }
    const int nact = lo;
    if (nact == 0) continue;          // uniform across block

    __syncthreads();                  // qs ready (pass0); prior-pass PV done with kv
    // stage K: kv[d*128 + key] = kraw[bh, d, k0+key]
    const float* kb = kraw + (size_t)bh * D_ * L_ + k0;
#pragma unroll
    for (int j = 0; j < 8; j++) {
      int e4 = 4 * (t + 256 * j);
      int d = e4 >> 7, key = e4 & 127;
      *(float4*)&kv[e4] = *(const float4*)&kb[(size_t)d * L_ + key];
    }
    __syncthreads();

    const int wr0 = 12 * w;
    if (wr0 < nact) {
      float s[3][8];
#pragma unroll
      for (int j = 0; j < 3; j++)
#pragma unroll
        for (int x = 0; x < 8; x++) s[j][x] = 0.f;
#pragma unroll 8
      for (int d = 0; d < 64; d++) {
        float4 ka = *(const float4*)&kv[d * 128 + 4 * kl];
        float4 kb2 = *(const float4*)&kv[d * 128 + 64 + 4 * kl];
#pragma unroll
        for (int j = 0; j < 3; j++) {
          float qd = qs[(wr0 + 3 * rg + j) * 68 + d];
          s[j][0] += qd * ka.x;  s[j][1] += qd * ka.y;
          s[j][2] += qd * ka.z;  s[j][3] += qd * ka.w;
          s[j][4] += qd * kb2.x; s[j][5] += qd * kb2.y;
          s[j][6] += qd * kb2.z; s[j][7] += qd * kb2.w;
        }
      }
#pragma unroll
      for (int j = 0; j < 3; j++) {
        const int R = wr0 + 3 * rg + j;
        const int sel = ssel[R];
        float mx = -INFINITY;
#pragma unroll
        for (int x = 0; x < 8; x++) {
          int kg = k0 + 4 * kl + (x < 4 ? x : 60 + x);   // keys 4kl+{0..3}, 64+4kl+{0..3}
          s[j][x] *= (1.0f / 32768.0f);
          if (kg > sel) s[j][x] = -INFINITY;
          mx = fmaxf(mx, s[j][x]);
        }
        mx = fmaxf(mx, __shfl_xor(mx, 1, 64));
        mx = fmaxf(mx, __shfl_xor(mx, 2, 64));
        mx = fmaxf(mx, __shfl_xor(mx, 4, 64));
        mx = fmaxf(mx, __shfl_xor(mx, 8, 64));
        float e[8], sm = 0.f;
#pragma unroll
        for (int x = 0; x < 8; x++) { e[x] = expf(s[j][x] - mx); sm += e[x]; }
        sm += __shfl_xor(sm, 1, 64);
        sm += __shfl_xor(sm, 2, 64);
        sm += __shfl_xor(sm, 4, 64);
        sm += __shfl_xor(sm, 8, 64);
        *(float4*)&eS[R * 132 + 4 * kl] = make_float4(e[0], e[1], e[2], e[3]);
        *(float4*)&eS[R * 132 + 64 + 4 * kl] = make_float4(e[4], e[5], e[6], e[7]);
        if (kl == 0 && R < nact) {
          float* p = part + ((size_t)(bh * TOPU + R) * NCH + ch) * PSTRIDE;
          p[64] = mx; p[65] = sm;
        }
      }
    }
    __syncthreads();
    // stage V: kv[key*64 + d] = vt[bh, k0+key, d] (linear copy)
    const float* vb = vt + ((size_t)bh * L_ + k0) * D_;
#pragma unroll
    for (int j = 0; j < 8; j++) {
      int e4 = 4 * (t + 256 * j);
      *(float4*)&kv[e4] = *(const float4*)&vb[e4];
    }
    __syncthreads();
    if (wr0 < nact) {
      float acc[3][4];
#pragma unroll
      for (int j = 0; j < 3; j++)
#pragma unroll
        for (int x = 0; x < 4; x++) acc[j][x] = 0.f;
#pragma unroll 8
      for (int kp = 0; kp < 64; kp++) {
        float4 v0 = *(const float4*)&kv[(2 * kp) * 64 + 4 * kl];
        float4 v1 = *(const float4*)&kv[(2 * kp + 1) * 64 + 4 * kl];
#pragma unroll
        for (int j = 0; j < 3; j++) {
          float2 ee = *(const float2*)&eS[(wr0 + 3 * rg + j) * 132 + 2 * kp];
          acc[j][0] += ee.x * v0.x + ee.y * v1.x;
          acc[j][1] += ee.x * v0.y + ee.y * v1.y;
          acc[j][2] += ee.x * v0.z + ee.y * v1.z;
          acc[j][3] += ee.x * v0.w + ee.y * v1.w;
        }
      }
#pragma unroll
      for (int j = 0; j < 3; j++) {
        const int R = wr0 + 3 * rg + j;
        if (R < nact) {
          float* p = part + ((size_t)(bh * TOPU + R) * NCH + ch) * PSTRIDE;
          *(float4*)&p[4 * kl] = *(float4*)&acc[j][0];
        }
      }
    }
  }
}

// ---------------- update phase 2: combine valid chunks + write column ----------------
__global__ __launch_bounds__(64) void update_combine(const float* __restrict__ part,
                                                     const int* __restrict__ ssel_g,
                                                     float* __restrict__ out) {
  const int row = blockIdx.x;                 // 0..BH*TOPU-1 (sorted order)
  const int bh = row / TOPU;
  const int sel = ssel_g[row];
  const int d = threadIdx.x;                  // 0..63
  const int nv = sel / CHUNK + 1;             // valid chunks
  const float* p = part + (size_t)row * NCH * PSTRIDE;

  float m = -INFINITY;
  for (int c = 0; c < nv; c++) m = fmaxf(m, p[c * PSTRIDE + 64]);

  float num = 0.0f, den = 0.0f;
  for (int c = 0; c < nv; c++) {
    float mc = p[c * PSTRIDE + 64];
    float wgt = expf(mc - m);
    num += wgt * p[c * PSTRIDE + d];
    den += wgt * p[c * PSTRIDE + 65];
  }
  out[((size_t)bh * D_ + d) * L_ + sel] = num / den;
}

extern "C" void kernel_launch(void* const* d_in, const int* in_sizes, int n_in,
                              void* d_out, int out_size, void* d_ws, size_t ws_size,
                              hipStream_t stream) {
  const float* q = (const float*)d_in[0];
  const float* k = (const float*)d_in[1];
  const float* v = (const float*)d_in[2];
  float* out = (float*)d_out;

  const size_t NT = (size_t)BH * L_ * D_;     // 8388608 floats per tensor
  float* qt = (float*)d_ws;
  float* kt = qt + NT;
  float* vt = kt + NT;
  float* M  = vt + NT;                         // BH*L floats
  int* idx  = (int*)(M + (size_t)BH * L_);     // 4096*25 ints
  int* ssel = idx + L_ * U_PART;               // BH*45 ints (sorted desc per bh)
  float* part = (float*)(ssel + BH * TOPU);    // 1440*32*68 floats (~12.5 MB)

  uint32_t k2a, k2b;
#if JAX_THREEFRY_PARTITIONABLE
  tf2x32(0u, 42u, 0u, 1u, k2a, k2b);
#else
  uint32_t a0, a1, b0, b1;
  tf2x32(0u, 42u, 0u, 2u, a0, a1);
  tf2x32(0u, 42u, 1u, 3u, b0, b1);
  k2a = a1; k2b = b1;
#endif

  transpose_scale<<<dim3(L_ / 64, BH, 3), 256, 0, stream>>>(q, k, v, qt, kt, vt);
#if JAX_THREEFRY_PARTITIONABLE
  sample_idx_kernel<<<(L_ * U_PART + 255) / 256, 256, 0, stream>>>(idx, k2a, k2b);
#else
  sample_idx_kernel<<<(L_ * U_PART / 2 + 255) / 256, 256, 0, stream>>>(idx, k2a, k2b);
#endif
  m_kernel<<<BH * L_ / 16, 256, 0, stream>>>(qt, kt, idx, M);
  topk_kernel<<<BH, 256, 0, stream>>>(M, ssel);
  cumsum_kernel<<<BH * D_, 256, 0, stream>>>(v, out);
  update_partial<<<BH * 16, 256, 0, stream>>>(qt, k, vt, ssel, part);
  update_combine<<<BH * TOPU, 64, 0, stream>>>(part, ssel, out);
}

// Round 6
// 201.940 us; speedup vs baseline: 4.2788x; 1.3532x over previous
//
#include <hip/hip_runtime.h>
#include <cstdint>

// Reference geometry (fixed problem)
constexpr int B_ = 4, H_ = 8, D_ = 64, L_ = 4096;
constexpr int BH = B_ * H_;          // 32
constexpr int U_PART = 25;           // FACTOR * ceil(log(64))
constexpr int TOPU = 45;             // FACTOR * ceil(log(4096))
constexpr int CHUNK = 128;           // keys per update chunk (LDS-staged)
constexpr int NCH = L_ / CHUNK;      // 32 chunks
constexpr int PSTRIDE = 68;          // acc[64], max, sum, pad to 16B-aligned stride

#define JAX_THREEFRY_PARTITIONABLE 1

// ---------------- Threefry-2x32 (exact JAX semantics) ----------------
__host__ __device__ inline void tf2x32(uint32_t k0, uint32_t k1,
                                       uint32_t x0, uint32_t x1,
                                       uint32_t& y0, uint32_t& y1) {
  const uint32_t ks2 = k0 ^ k1 ^ 0x1BD11BDAu;
  uint32_t v0 = x0 + k0, v1 = x1 + k1;
#define RND(r) { v0 += v1; v1 = (v1 << (r)) | (v1 >> (32 - (r))); v1 ^= v0; }
  RND(13) RND(15) RND(26) RND(6)
  v0 += k1; v1 += ks2 + 1u;
  RND(17) RND(29) RND(16) RND(24)
  v0 += ks2; v1 += k0 + 2u;
  RND(13) RND(15) RND(26) RND(6)
  v0 += k0; v1 += k1 + 3u;
  RND(17) RND(29) RND(16) RND(24)
  v0 += k1; v1 += ks2 + 4u;
  RND(13) RND(15) RND(26) RND(6)
  v0 += ks2; v1 += k0 + 5u;
#undef RND
  y0 = v0; y1 = v1;
}

__global__ __launch_bounds__(256) void sample_idx_kernel(int* __restrict__ idx,
                                                         uint32_t k2a, uint32_t k2b) {
#if JAX_THREEFRY_PARTITIONABLE
  int i = blockIdx.x * 256 + threadIdx.x;
  if (i >= L_ * U_PART) return;
  uint32_t y0, y1;
  tf2x32(k2a, k2b, 0u, (uint32_t)i, y0, y1);
  idx[i] = (int)((y0 ^ y1) & 4095u);
#else
  int j = blockIdx.x * 256 + threadIdx.x;
  const int half = (L_ * U_PART) / 2;   // 51200
  if (j >= half) return;
  uint32_t y0, y1;
  tf2x32(k2a, k2b, (uint32_t)j, (uint32_t)(j + half), y0, y1);
  idx[j] = (int)(y0 & 4095u);
  idx[j + half] = (int)(y1 & 4095u);
#endif
}

// ---------------- Transpose + scale: (BH, D, L) -> (BH, L, D) ----------------
__global__ __launch_bounds__(256) void transpose_scale(
    const float* __restrict__ q, const float* __restrict__ k, const float* __restrict__ v,
    float* __restrict__ qt, float* __restrict__ kt, float* __restrict__ vt) {
  const float* src; float* dst; float scale;
  if (blockIdx.z == 0)      { src = q; dst = qt; scale = 1.0f / 512.0f; }
  else if (blockIdx.z == 1) { src = k; dst = kt; scale = 1.0f / 64.0f; }
  else                      { src = v; dst = vt; scale = 1.0f / 64.0f; }
  const int bh = blockIdx.y;
  const int l0 = blockIdx.x * 64;
  __shared__ float tile[64][65];
  const float* s = src + (size_t)bh * D_ * L_;
  float* d = dst + (size_t)bh * L_ * D_;
  const int t = threadIdx.x;
#pragma unroll
  for (int i = 0; i < 16; i++) {
    int li = i * 256 + t;          // 0..4095
    int dd = li >> 6, ll = li & 63;
    tile[dd][ll] = s[(size_t)dd * L_ + l0 + ll] * scale;
  }
  __syncthreads();
#pragma unroll
  for (int i = 0; i < 16; i++) {
    int li = i * 256 + t;
    int ll = li >> 6, dd = li & 63;
    d[(size_t)(l0 + ll) * D_ + dd] = tile[dd][ll];
  }
}

// ---------------- M[b,h,l] = max_s QK - sum_s QK / 4096 ----------------
// 16 lanes per l (float4 fragments), 4 l per wave, 16 l per block.
__global__ __launch_bounds__(256) void m_kernel(const float* __restrict__ qt,
                                                const float* __restrict__ kt,
                                                const int* __restrict__ idx,
                                                float* __restrict__ M) {
  const int t = threadIdx.x;
  const int w = t >> 6, lane = t & 63;
  const int g = lane >> 4, gl = lane & 15;     // group in wave, lane in group
  const int gidx = blockIdx.x * 16 + w * 4 + g;   // 0..BH*L-1
  const int bh = gidx >> 12, l = gidx & (L_ - 1);
  const float* qtb = qt + (size_t)bh * L_ * D_;
  const float* ktb = kt + (size_t)bh * L_ * D_;
  const float4 ql = *(const float4*)(qtb + (size_t)l * D_ + gl * 4);
  const int* ip = idx + l * U_PART;
  float mx = -INFINITY, sm = 0.0f;
#pragma unroll 5
  for (int s = 0; s < U_PART; s++) {
    int ki = ip[s];
    float4 kk = *(const float4*)(ktb + (size_t)ki * D_ + gl * 4);
    float p = ql.x * kk.x + ql.y * kk.y + ql.z * kk.z + ql.w * kk.w;
    p += __shfl_xor(p, 8, 64);
    p += __shfl_xor(p, 4, 64);
    p += __shfl_xor(p, 2, 64);
    p += __shfl_xor(p, 1, 64);
    mx = fmaxf(mx, p);
    sm += p;
  }
  if (gl == 0) M[gidx] = mx - sm * (1.0f / 4096.0f);
}

// ---------------- top-45 per (b,h), register-resident, SORTED DESC by index ----------------
// 4 waves x 64 lanes x 16 values in VGPRs. Keys packed (mapped_val << 32) | (4095-idx)
// so u64 max gives lax.top_k tie semantics (lowest index on equal value).
__global__ __launch_bounds__(256) void topk_kernel(const float* __restrict__ M,
                                                   int* __restrict__ ssel_g) {
  const int bh = blockIdx.x, t = threadIdx.x;
  const int w = t >> 6, lane = t & 63;
  const float* Mb = M + (size_t)bh * L_;
  const int base = w * 1024 + lane;
  uint32_t v[16];
#pragma unroll
  for (int j = 0; j < 16; j++) {          // coalesced: lanes read consecutive
    uint32_t b = __float_as_uint(Mb[base + j * 64]);
    v[j] = b ^ ((b & 0x80000000u) ? 0xFFFFFFFFu : 0x80000000u);
  }
  __shared__ unsigned long long red[4];
  __shared__ int picks[TOPU];
  for (int it = 0; it < TOPU; it++) {
    unsigned long long best = 0ull;
#pragma unroll
    for (int j = 0; j < 16; j++) {
      unsigned long long key = ((unsigned long long)v[j] << 32)
                             | (uint32_t)(L_ - 1 - (base + j * 64));
      best = (key > best) ? key : best;
    }
#pragma unroll
    for (int off = 32; off; off >>= 1) {
      unsigned long long o = __shfl_xor(best, off, 64);
      best = (o > best) ? o : best;
    }
    if (lane == 0) red[w] = best;
    __syncthreads();
    unsigned long long g = red[0];
    if (red[1] > g) g = red[1];
    if (red[2] > g) g = red[2];
    if (red[3] > g) g = red[3];
    const int bi = L_ - 1 - (int)(g & 0xFFFFFFFFu);
    if (t == 0) picks[it] = bi;
    if ((bi >> 10) == w && (bi & 63) == lane) {   // remove winner (predicated, static idx)
      const int slot = (bi >> 6) & 15;
#pragma unroll
      for (int j = 0; j < 16; j++) if (slot == j) v[j] = 0u;
    }
    __syncthreads();                      // red/picks stable before next overwrite
  }
  // rank-sort descending by key index (indices distinct)
  if (t < TOPU) {
    int my = picks[t];
    int rank = 0;
    for (int j = 0; j < TOPU; j++) rank += (picks[j] > my);
    ssel_g[bh * TOPU + rank] = my;
  }
}

// ---------------- out[bh,d,l] = cumsum_l v[bh,d,l] / 64 ----------------
__global__ __launch_bounds__(256) void cumsum_kernel(const float* __restrict__ v,
                                                     float* __restrict__ out) {
  const int row = blockIdx.x;                 // BH*D rows
  const float* src = v + (size_t)row * L_;
  float* dst = out + (size_t)row * L_;
  const int t = threadIdx.x;
  float vals[16];
  const float4* s4 = (const float4*)(src + t * 16);
#pragma unroll
  for (int i = 0; i < 4; i++) {
    float4 x = s4[i];
    vals[4 * i + 0] = x.x; vals[4 * i + 1] = x.y;
    vals[4 * i + 2] = x.z; vals[4 * i + 3] = x.w;
  }
  float run = 0.0f;
#pragma unroll
  for (int i = 0; i < 16; i++) { run += vals[i] * (1.0f / 64.0f); vals[i] = run; }
  float x = run;
#pragma unroll
  for (int off = 1; off < 64; off <<= 1) {
    float y = __shfl_up(x, off, 64);
    if ((t & 63) >= off) x += y;
  }
  __shared__ float wtot[4];
  if ((t & 63) == 63) wtot[t >> 6] = x;
  __syncthreads();
  float woff = 0.0f;
  for (int w = 0; w < (t >> 6); w++) woff += wtot[w];
  const float excl = x - run + woff;
#pragma unroll
  for (int i = 0; i < 16; i++) vals[i] += excl;
  float4* d4 = (float4*)(dst + t * 16);
#pragma unroll
  for (int i = 0; i < 4; i++)
    d4[i] = make_float4(vals[4 * i], vals[4 * i + 1], vals[4 * i + 2], vals[4 * i + 3]);
}

// ---------------- update phase 1: register-tiled GEMM per (bh, chunk-pair) ----------------
__global__ __launch_bounds__(256) void update_partial(const float* __restrict__ qt,
                                                      const float* __restrict__ kraw,
                                                      const float* __restrict__ vt,
                                                      const int* __restrict__ ssel_g,
                                                      float* __restrict__ part) {
  const int bidx = blockIdx.x;        // 0..511
  const int bh = bidx >> 4;
  const int ch0 = bidx & 15;
  const int t = threadIdx.x;
  const int w = t >> 6, lane = t & 63;
  const int kl = lane & 15, rg = lane >> 4;

  __shared__ float kv[CHUNK * 64];    // 32KB: kS[d][128] then vS[key][64]
  __shared__ float qs[48 * 68];       // padded stride 68
  __shared__ float eS[48 * 132];      // padded stride 132
  __shared__ int ssel[48];

  if (t < 48) ssel[t] = (t < TOPU) ? ssel_g[bh * TOPU + t] : -1;
  __syncthreads();

  // stage Q: 48 rows x 64 d (rows 45..47 zero)
#pragma unroll
  for (int j = 0; j < 3; j++) {
    int it = t + 256 * j;             // 0..767
    int rr = it >> 4, dc = it & 15;
    int sel = ssel[rr];
    float4 qv = make_float4(0.f, 0.f, 0.f, 0.f);
    if (sel >= 0) qv = *(const float4*)&qt[((size_t)bh * L_ + sel) * D_ + 4 * dc];
    *(float4*)&qs[rr * 68 + 4 * dc] = qv;
  }

  for (int pass = 0; pass < 2; pass++) {
    const int ch = pass ? (31 - ch0) : ch0;
    const int k0 = ch * CHUNK;
    int lo = 0, hi = TOPU;
    while (lo < hi) { int mid = (lo + hi) >> 1; if (ssel[mid] >= k0) lo = mid + 1; else hi = mid; }
    const int nact = lo;
    if (nact == 0) continue;          // uniform across block

    __syncthreads();
    // stage K: kv[d*128 + key] = kraw[bh, d, k0+key]
    const float* kb = kraw + (size_t)bh * D_ * L_ + k0;
#pragma unroll
    for (int j = 0; j < 8; j++) {
      int e4 = 4 * (t + 256 * j);
      int d = e4 >> 7, key = e4 & 127;
      *(float4*)&kv[e4] = *(const float4*)&kb[(size_t)d * L_ + key];
    }
    __syncthreads();

    const int wr0 = 12 * w;
    if (wr0 < nact) {
      float s[3][8];
#pragma unroll
      for (int j = 0; j < 3; j++)
#pragma unroll
        for (int x = 0; x < 8; x++) s[j][x] = 0.f;
#pragma unroll 8
      for (int d = 0; d < 64; d++) {
        float4 ka = *(const float4*)&kv[d * 128 + 4 * kl];
        float4 kb2 = *(const float4*)&kv[d * 128 + 64 + 4 * kl];
#pragma unroll
        for (int j = 0; j < 3; j++) {
          float qd = qs[(wr0 + 3 * rg + j) * 68 + d];
          s[j][0] += qd * ka.x;  s[j][1] += qd * ka.y;
          s[j][2] += qd * ka.z;  s[j][3] += qd * ka.w;
          s[j][4] += qd * kb2.x; s[j][5] += qd * kb2.y;
          s[j][6] += qd * kb2.z; s[j][7] += qd * kb2.w;
        }
      }
#pragma unroll
      for (int j = 0; j < 3; j++) {
        const int R = wr0 + 3 * rg + j;
        const int sel = ssel[R];
        float mx = -INFINITY;
#pragma unroll
        for (int x = 0; x < 8; x++) {
          int kg = k0 + 4 * kl + (x < 4 ? x : 60 + x);   // keys 4kl+{0..3}, 64+4kl+{0..3}
          s[j][x] *= (1.0f / 32768.0f);
          if (kg > sel) s[j][x] = -INFINITY;
          mx = fmaxf(mx, s[j][x]);
        }
        mx = fmaxf(mx, __shfl_xor(mx, 1, 64));
        mx = fmaxf(mx, __shfl_xor(mx, 2, 64));
        mx = fmaxf(mx, __shfl_xor(mx, 4, 64));
        mx = fmaxf(mx, __shfl_xor(mx, 8, 64));
        float e[8], sm = 0.f;
#pragma unroll
        for (int x = 0; x < 8; x++) { e[x] = expf(s[j][x] - mx); sm += e[x]; }
        sm += __shfl_xor(sm, 1, 64);
        sm += __shfl_xor(sm, 2, 64);
        sm += __shfl_xor(sm, 4, 64);
        sm += __shfl_xor(sm, 8, 64);
        *(float4*)&eS[R * 132 + 4 * kl] = make_float4(e[0], e[1], e[2], e[3]);
        *(float4*)&eS[R * 132 + 64 + 4 * kl] = make_float4(e[4], e[5], e[6], e[7]);
        if (kl == 0 && R < nact) {
          float* p = part + ((size_t)(bh * TOPU + R) * NCH + ch) * PSTRIDE;
          p[64] = mx; p[65] = sm;
        }
      }
    }
    __syncthreads();
    // stage V: kv[key*64 + d] = vt[bh, k0+key, d] (linear copy)
    const float* vb = vt + ((size_t)bh * L_ + k0) * D_;
#pragma unroll
    for (int j = 0; j < 8; j++) {
      int e4 = 4 * (t + 256 * j);
      *(float4*)&kv[e4] = *(const float4*)&vb[e4];
    }
    __syncthreads();
    if (wr0 < nact) {
      float acc[3][4];
#pragma unroll
      for (int j = 0; j < 3; j++)
#pragma unroll
        for (int x = 0; x < 4; x++) acc[j][x] = 0.f;
#pragma unroll 8
      for (int kp = 0; kp < 64; kp++) {
        float4 v0 = *(const float4*)&kv[(2 * kp) * 64 + 4 * kl];
        float4 v1 = *(const float4*)&kv[(2 * kp + 1) * 64 + 4 * kl];
#pragma unroll
        for (int j = 0; j < 3; j++) {
          float2 ee = *(const float2*)&eS[(wr0 + 3 * rg + j) * 132 + 2 * kp];
          acc[j][0] += ee.x * v0.x + ee.y * v1.x;
          acc[j][1] += ee.x * v0.y + ee.y * v1.y;
          acc[j][2] += ee.x * v0.z + ee.y * v1.z;
          acc[j][3] += ee.x * v0.w + ee.y * v1.w;
        }
      }
#pragma unroll
      for (int j = 0; j < 3; j++) {
        const int R = wr0 + 3 * rg + j;
        if (R < nact) {
          float* p = part + ((size_t)(bh * TOPU + R) * NCH + ch) * PSTRIDE;
          *(float4*)&p[4 * kl] = *(float4*)&acc[j][0];
        }
      }
    }
  }
}

// ---------------- update phase 2: combine valid chunks + write column ----------------
__global__ __launch_bounds__(64) void update_combine(const float* __restrict__ part,
                                                     const int* __restrict__ ssel_g,
                                                     float* __restrict__ out) {
  const int row = blockIdx.x;                 // 0..BH*TOPU-1 (sorted order)
  const int bh = row / TOPU;
  const int sel = ssel_g[row];
  const int d = threadIdx.x;                  // 0..63
  const int nv = sel / CHUNK + 1;             // valid chunks
  const float* p = part + (size_t)row * NCH * PSTRIDE;

  float m = -INFINITY;
  for (int c = 0; c < nv; c++) m = fmaxf(m, p[c * PSTRIDE + 64]);

  float num = 0.0f, den = 0.0f;
  for (int c = 0; c < nv; c++) {
    float mc = p[c * PSTRIDE + 64];
    float wgt = expf(mc - m);
    num += wgt * p[c * PSTRIDE + d];
    den += wgt * p[c * PSTRIDE + 65];
  }
  out[((size_t)bh * D_ + d) * L_ + sel] = num / den;
}

extern "C" void kernel_launch(void* const* d_in, const int* in_sizes, int n_in,
                              void* d_out, int out_size, void* d_ws, size_t ws_size,
                              hipStream_t stream) {
  const float* q = (const float*)d_in[0];
  const float* k = (const float*)d_in[1];
  const float* v = (const float*)d_in[2];
  float* out = (float*)d_out;

  const size_t NT = (size_t)BH * L_ * D_;     // 8388608 floats per tensor
  float* qt = (float*)d_ws;
  float* kt = qt + NT;
  float* vt = kt + NT;
  float* M  = vt + NT;                         // BH*L floats
  int* idx  = (int*)(M + (size_t)BH * L_);     // 4096*25 ints
  int* ssel = idx + L_ * U_PART;               // BH*45 ints (sorted desc per bh)
  float* part = (float*)(ssel + BH * TOPU);    // 1440*32*68 floats (~12.5 MB)

  uint32_t k2a, k2b;
#if JAX_THREEFRY_PARTITIONABLE
  tf2x32(0u, 42u, 0u, 1u, k2a, k2b);
#else
  uint32_t a0, a1, b0, b1;
  tf2x32(0u, 42u, 0u, 2u, a0, a1);
  tf2x32(0u, 42u, 1u, 3u, b0, b1);
  k2a = a1; k2b = b1;
#endif

  transpose_scale<<<dim3(L_ / 64, BH, 3), 256, 0, stream>>>(q, k, v, qt, kt, vt);
#if JAX_THREEFRY_PARTITIONABLE
  sample_idx_kernel<<<(L_ * U_PART + 255) / 256, 256, 0, stream>>>(idx, k2a, k2b);
#else
  sample_idx_kernel<<<(L_ * U_PART / 2 + 255) / 256, 256, 0, stream>>>(idx, k2a, k2b);
#endif
  m_kernel<<<BH * L_ / 16, 256, 0, stream>>>(qt, kt, idx, M);
  topk_kernel<<<BH, 256, 0, stream>>>(M, ssel);
  cumsum_kernel<<<BH * D_, 256, 0, stream>>>(v, out);
  update_partial<<<BH * 16, 256, 0, stream>>>(qt, k, vt, ssel, part);
  update_combine<<<BH * TOPU, 64, 0, stream>>>(part, ssel, out);
}

// Round 7
// 181.771 us; speedup vs baseline: 4.7536x; 1.1110x over previous
//
#include <hip/hip_runtime.h>
#include <cstdint>

// Reference geometry (fixed problem)
constexpr int B_ = 4, H_ = 8, D_ = 64, L_ = 4096;
constexpr int BH = B_ * H_;          // 32
constexpr int U_PART = 25;           // FACTOR * ceil(log(64))
constexpr int TOPU = 45;             // FACTOR * ceil(log(4096))
constexpr int CHUNK = 128;           // keys per update chunk (LDS-staged)
constexpr int NCH = L_ / CHUNK;      // 32 chunks
constexpr int PSTRIDE = 68;          // acc[64], max, sum, pad to 16B-aligned stride

#define JAX_THREEFRY_PARTITIONABLE 1

// ---------------- Threefry-2x32 (exact JAX semantics) ----------------
__host__ __device__ inline void tf2x32(uint32_t k0, uint32_t k1,
                                       uint32_t x0, uint32_t x1,
                                       uint32_t& y0, uint32_t& y1) {
  const uint32_t ks2 = k0 ^ k1 ^ 0x1BD11BDAu;
  uint32_t v0 = x0 + k0, v1 = x1 + k1;
#define RND(r) { v0 += v1; v1 = (v1 << (r)) | (v1 >> (32 - (r))); v1 ^= v0; }
  RND(13) RND(15) RND(26) RND(6)
  v0 += k1; v1 += ks2 + 1u;
  RND(17) RND(29) RND(16) RND(24)
  v0 += ks2; v1 += k0 + 2u;
  RND(13) RND(15) RND(26) RND(6)
  v0 += k0; v1 += k1 + 3u;
  RND(17) RND(29) RND(16) RND(24)
  v0 += k1; v1 += ks2 + 4u;
  RND(13) RND(15) RND(26) RND(6)
  v0 += ks2; v1 += k0 + 5u;
#undef RND
  y0 = v0; y1 = v1;
}

__global__ __launch_bounds__(256) void sample_idx_kernel(int* __restrict__ idx,
                                                         uint32_t k2a, uint32_t k2b) {
#if JAX_THREEFRY_PARTITIONABLE
  int i = blockIdx.x * 256 + threadIdx.x;
  if (i >= L_ * U_PART) return;
  uint32_t y0, y1;
  tf2x32(k2a, k2b, 0u, (uint32_t)i, y0, y1);
  idx[i] = (int)((y0 ^ y1) & 4095u);
#else
  int j = blockIdx.x * 256 + threadIdx.x;
  const int half = (L_ * U_PART) / 2;   // 51200
  if (j >= half) return;
  uint32_t y0, y1;
  tf2x32(k2a, k2b, (uint32_t)j, (uint32_t)(j + half), y0, y1);
  idx[j] = (int)(y0 & 4095u);
  idx[j + half] = (int)(y1 & 4095u);
#endif
}

// ---------------- Transpose + scale: (BH, D, L) -> (BH, L, D) ----------------
__global__ __launch_bounds__(256) void transpose_scale(
    const float* __restrict__ q, const float* __restrict__ k, const float* __restrict__ v,
    float* __restrict__ qt, float* __restrict__ kt, float* __restrict__ vt) {
  const float* src; float* dst; float scale;
  if (blockIdx.z == 0)      { src = q; dst = qt; scale = 1.0f / 512.0f; }
  else if (blockIdx.z == 1) { src = k; dst = kt; scale = 1.0f / 64.0f; }
  else                      { src = v; dst = vt; scale = 1.0f / 64.0f; }
  const int bh = blockIdx.y;
  const int l0 = blockIdx.x * 64;
  __shared__ float tile[64][65];
  const float* s = src + (size_t)bh * D_ * L_;
  float* d = dst + (size_t)bh * L_ * D_;
  const int t = threadIdx.x;
#pragma unroll
  for (int i = 0; i < 16; i++) {
    int li = i * 256 + t;          // 0..4095
    int dd = li >> 6, ll = li & 63;
    tile[dd][ll] = s[(size_t)dd * L_ + l0 + ll] * scale;
  }
  __syncthreads();
#pragma unroll
  for (int i = 0; i < 16; i++) {
    int li = i * 256 + t;
    int ll = li >> 6, dd = li & 63;
    d[(size_t)(l0 + ll) * D_ + dd] = tile[dd][ll];
  }
}

// ---------------- M[b,h,l] = max_s QK - sum_s QK / 4096 ----------------
// 16 lanes per l; XCD-swizzled so each XCD owns 4 bh (kt stays L2-resident).
__global__ __launch_bounds__(256) void m_kernel(const float* __restrict__ qt,
                                                const float* __restrict__ kt,
                                                const int* __restrict__ idx,
                                                float* __restrict__ M) {
  const int t = threadIdx.x;
  const int w = t >> 6, lane = t & 63;
  const int g = lane >> 4, gl = lane & 15;     // group in wave, lane in group
  // blockIdx%8 = XCD [m09]; 1024 slots/XCD = 4 bh x 256 l-groups
  const int xcd = blockIdx.x & 7;
  const int slot = blockIdx.x >> 3;            // 0..1023
  const int bh = xcd * 4 + (slot >> 8);
  const int lg = slot & 255;
  const int l = lg * 16 + w * 4 + g;
  const int gidx = bh * L_ + l;
  const float* qtb = qt + (size_t)bh * L_ * D_;
  const float* ktb = kt + (size_t)bh * L_ * D_;
  const float4 ql = *(const float4*)(qtb + (size_t)l * D_ + gl * 4);
  const int* ip = idx + l * U_PART;
  float mx = -INFINITY, sm = 0.0f;
#pragma unroll 5
  for (int s = 0; s < U_PART; s++) {
    int ki = ip[s];
    float4 kk = *(const float4*)(ktb + (size_t)ki * D_ + gl * 4);
    float p = ql.x * kk.x + ql.y * kk.y + ql.z * kk.z + ql.w * kk.w;
    p += __shfl_xor(p, 8, 64);
    p += __shfl_xor(p, 4, 64);
    p += __shfl_xor(p, 2, 64);
    p += __shfl_xor(p, 1, 64);
    mx = fmaxf(mx, p);
    sm += p;
  }
  if (gl == 0) M[gidx] = mx - sm * (1.0f / 4096.0f);
}

// ---------------- top-45 per (b,h), register-resident, SORTED DESC by index ----------------
__global__ __launch_bounds__(256) void topk_kernel(const float* __restrict__ M,
                                                   int* __restrict__ ssel_g) {
  const int bh = blockIdx.x, t = threadIdx.x;
  const int w = t >> 6, lane = t & 63;
  const float* Mb = M + (size_t)bh * L_;
  const int base = w * 1024 + lane;
  uint32_t v[16];
#pragma unroll
  for (int j = 0; j < 16; j++) {          // coalesced: lanes read consecutive
    uint32_t b = __float_as_uint(Mb[base + j * 64]);
    v[j] = b ^ ((b & 0x80000000u) ? 0xFFFFFFFFu : 0x80000000u);
  }
  __shared__ unsigned long long red[4];
  __shared__ int picks[TOPU];
  for (int it = 0; it < TOPU; it++) {
    unsigned long long best = 0ull;
#pragma unroll
    for (int j = 0; j < 16; j++) {
      unsigned long long key = ((unsigned long long)v[j] << 32)
                             | (uint32_t)(L_ - 1 - (base + j * 64));
      best = (key > best) ? key : best;
    }
#pragma unroll
    for (int off = 32; off; off >>= 1) {
      unsigned long long o = __shfl_xor(best, off, 64);
      best = (o > best) ? o : best;
    }
    if (lane == 0) red[w] = best;
    __syncthreads();
    unsigned long long g = red[0];
    if (red[1] > g) g = red[1];
    if (red[2] > g) g = red[2];
    if (red[3] > g) g = red[3];
    const int bi = L_ - 1 - (int)(g & 0xFFFFFFFFu);
    if (t == 0) picks[it] = bi;
    if ((bi >> 10) == w && (bi & 63) == lane) {   // remove winner
      const int slot = (bi >> 6) & 15;
#pragma unroll
      for (int j = 0; j < 16; j++) if (slot == j) v[j] = 0u;
    }
    __syncthreads();
  }
  // rank-sort descending by key index (indices distinct)
  if (t < TOPU) {
    int my = picks[t];
    int rank = 0;
    for (int j = 0; j < TOPU; j++) rank += (picks[j] > my);
    ssel_g[bh * TOPU + rank] = my;
  }
}

// ---------------- out[bh,d,l] = cumsum_l v[bh,d,l] / 64 ----------------
__global__ __launch_bounds__(256) void cumsum_kernel(const float* __restrict__ v,
                                                     float* __restrict__ out) {
  const int row = blockIdx.x;                 // BH*D rows
  const float* src = v + (size_t)row * L_;
  float* dst = out + (size_t)row * L_;
  const int t = threadIdx.x;
  float vals[16];
  const float4* s4 = (const float4*)(src + t * 16);
#pragma unroll
  for (int i = 0; i < 4; i++) {
    float4 x = s4[i];
    vals[4 * i + 0] = x.x; vals[4 * i + 1] = x.y;
    vals[4 * i + 2] = x.z; vals[4 * i + 3] = x.w;
  }
  float run = 0.0f;
#pragma unroll
  for (int i = 0; i < 16; i++) { run += vals[i] * (1.0f / 64.0f); vals[i] = run; }
  float x = run;
#pragma unroll
  for (int off = 1; off < 64; off <<= 1) {
    float y = __shfl_up(x, off, 64);
    if ((t & 63) >= off) x += y;
  }
  __shared__ float wtot[4];
  if ((t & 63) == 63) wtot[t >> 6] = x;
  __syncthreads();
  float woff = 0.0f;
  for (int w = 0; w < (t >> 6); w++) woff += wtot[w];
  const float excl = x - run + woff;
#pragma unroll
  for (int i = 0; i < 16; i++) vals[i] += excl;
  float4* d4 = (float4*)(dst + t * 16);
#pragma unroll
  for (int i = 0; i < 4; i++)
    d4[i] = make_float4(vals[4 * i], vals[4 * i + 1], vals[4 * i + 2], vals[4 * i + 3]);
}

// ---------------- update phase 1: register-tiled GEMM per (bh, chunk-pair) ----------------
// XCD-swizzled: each XCD owns 4 bh (kraw/vt/qt slices stay L2-local).
__global__ __launch_bounds__(256) void update_partial(const float* __restrict__ qt,
                                                      const float* __restrict__ kraw,
                                                      const float* __restrict__ vt,
                                                      const int* __restrict__ ssel_g,
                                                      float* __restrict__ part) {
  const int xcd = blockIdx.x & 7;
  const int slot = blockIdx.x >> 3;   // 0..63
  const int bh = xcd * 4 + (slot >> 4);
  const int ch0 = slot & 15;
  const int t = threadIdx.x;
  const int w = t >> 6, lane = t & 63;
  const int kl = lane & 15, rg = lane >> 4;

  __shared__ float kv[CHUNK * 64];    // 32KB: kS[d][128] then vS[key][64]
  __shared__ float qs[48 * 68];       // padded stride 68
  __shared__ float eS[48 * 132];      // padded stride 132
  __shared__ int ssel[48];

  if (t < 48) ssel[t] = (t < TOPU) ? ssel_g[bh * TOPU + t] : -1;
  __syncthreads();

  // stage Q: 48 rows x 64 d (rows 45..47 zero)
#pragma unroll
  for (int j = 0; j < 3; j++) {
    int it = t + 256 * j;             // 0..767
    int rr = it >> 4, dc = it & 15;
    int sel = ssel[rr];
    float4 qv = make_float4(0.f, 0.f, 0.f, 0.f);
    if (sel >= 0) qv = *(const float4*)&qt[((size_t)bh * L_ + sel) * D_ + 4 * dc];
    *(float4*)&qs[rr * 68 + 4 * dc] = qv;
  }

  for (int pass = 0; pass < 2; pass++) {
    const int ch = pass ? (31 - ch0) : ch0;
    const int k0 = ch * CHUNK;
    int lo = 0, hi = TOPU;
    while (lo < hi) { int mid = (lo + hi) >> 1; if (ssel[mid] >= k0) lo = mid + 1; else hi = mid; }
    const int nact = lo;
    if (nact == 0) continue;          // uniform across block

    __syncthreads();
    // stage K: kv[d*128 + key] = kraw[bh, d, k0+key]
    const float* kb = kraw + (size_t)bh * D_ * L_ + k0;
#pragma unroll
    for (int j = 0; j < 8; j++) {
      int e4 = 4 * (t + 256 * j);
      int d = e4 >> 7, key = e4 & 127;
      *(float4*)&kv[e4] = *(const float4*)&kb[(size_t)d * L_ + key];
    }
    __syncthreads();

    const int wr0 = 12 * w;
    if (wr0 < nact) {
      float s[3][8];
#pragma unroll
      for (int j = 0; j < 3; j++)
#pragma unroll
        for (int x = 0; x < 8; x++) s[j][x] = 0.f;
#pragma unroll 8
      for (int d = 0; d < 64; d++) {
        float4 ka = *(const float4*)&kv[d * 128 + 4 * kl];
        float4 kb2 = *(const float4*)&kv[d * 128 + 64 + 4 * kl];
#pragma unroll
        for (int j = 0; j < 3; j++) {
          float qd = qs[(wr0 + 3 * rg + j) * 68 + d];
          s[j][0] += qd * ka.x;  s[j][1] += qd * ka.y;
          s[j][2] += qd * ka.z;  s[j][3] += qd * ka.w;
          s[j][4] += qd * kb2.x; s[j][5] += qd * kb2.y;
          s[j][6] += qd * kb2.z; s[j][7] += qd * kb2.w;
        }
      }
#pragma unroll
      for (int j = 0; j < 3; j++) {
        const int R = wr0 + 3 * rg + j;
        const int sel = ssel[R];
        float mx = -INFINITY;
#pragma unroll
        for (int x = 0; x < 8; x++) {
          int kg = k0 + 4 * kl + (x < 4 ? x : 60 + x);   // keys 4kl+{0..3}, 64+4kl+{0..3}
          s[j][x] *= (1.0f / 32768.0f);
          if (kg > sel) s[j][x] = -INFINITY;
          mx = fmaxf(mx, s[j][x]);
        }
        mx = fmaxf(mx, __shfl_xor(mx, 1, 64));
        mx = fmaxf(mx, __shfl_xor(mx, 2, 64));
        mx = fmaxf(mx, __shfl_xor(mx, 4, 64));
        mx = fmaxf(mx, __shfl_xor(mx, 8, 64));
        float e[8], sm = 0.f;
#pragma unroll
        for (int x = 0; x < 8; x++) { e[x] = expf(s[j][x] - mx); sm += e[x]; }
        sm += __shfl_xor(sm, 1, 64);
        sm += __shfl_xor(sm, 2, 64);
        sm += __shfl_xor(sm, 4, 64);
        sm += __shfl_xor(sm, 8, 64);
        *(float4*)&eS[R * 132 + 4 * kl] = make_float4(e[0], e[1], e[2], e[3]);
        *(float4*)&eS[R * 132 + 64 + 4 * kl] = make_float4(e[4], e[5], e[6], e[7]);
        if (kl == 0 && R < nact) {
          float* p = part + ((size_t)(bh * TOPU + R) * NCH + ch) * PSTRIDE;
          p[64] = mx; p[65] = sm;
        }
      }
    }
    __syncthreads();
    // stage V: kv[key*64 + d] = vt[bh, k0+key, d] (linear copy)
    const float* vb = vt + ((size_t)bh * L_ + k0) * D_;
#pragma unroll
    for (int j = 0; j < 8; j++) {
      int e4 = 4 * (t + 256 * j);
      *(float4*)&kv[e4] = *(const float4*)&vb[e4];
    }
    __syncthreads();
    if (wr0 < nact) {
      float acc[3][4];
#pragma unroll
      for (int j = 0; j < 3; j++)
#pragma unroll
        for (int x = 0; x < 4; x++) acc[j][x] = 0.f;
#pragma unroll 8
      for (int kp = 0; kp < 64; kp++) {
        float4 v0 = *(const float4*)&kv[(2 * kp) * 64 + 4 * kl];
        float4 v1 = *(const float4*)&kv[(2 * kp + 1) * 64 + 4 * kl];
#pragma unroll
        for (int j = 0; j < 3; j++) {
          float2 ee = *(const float2*)&eS[(wr0 + 3 * rg + j) * 132 + 2 * kp];
          acc[j][0] += ee.x * v0.x + ee.y * v1.x;
          acc[j][1] += ee.x * v0.y + ee.y * v1.y;
          acc[j][2] += ee.x * v0.z + ee.y * v1.z;
          acc[j][3] += ee.x * v0.w + ee.y * v1.w;
        }
      }
#pragma unroll
      for (int j = 0; j < 3; j++) {
        const int R = wr0 + 3 * rg + j;
        if (R < nact) {
          float* p = part + ((size_t)(bh * TOPU + R) * NCH + ch) * PSTRIDE;
          *(float4*)&p[4 * kl] = *(float4*)&acc[j][0];
        }
      }
    }
  }
}

// ---------------- update phase 2: combine valid chunks + write column ----------------
__global__ __launch_bounds__(64) void update_combine(const float* __restrict__ part,
                                                     const int* __restrict__ ssel_g,
                                                     float* __restrict__ out) {
  const int row = blockIdx.x;                 // 0..BH*TOPU-1 (sorted order)
  const int bh = row / TOPU;
  const int sel = ssel_g[row];
  const int d = threadIdx.x;                  // 0..63
  const int nv = sel / CHUNK + 1;             // valid chunks
  const float* p = part + (size_t)row * NCH * PSTRIDE;

  float m = -INFINITY;
  for (int c = 0; c < nv; c++) m = fmaxf(m, p[c * PSTRIDE + 64]);

  float num = 0.0f, den = 0.0f;
  for (int c = 0; c < nv; c++) {
    float mc = p[c * PSTRIDE + 64];
    float wgt = expf(mc - m);
    num += wgt * p[c * PSTRIDE + d];
    den += wgt * p[c * PSTRIDE + 65];
  }
  out[((size_t)bh * D_ + d) * L_ + sel] = num / den;
}

extern "C" void kernel_launch(void* const* d_in, const int* in_sizes, int n_in,
                              void* d_out, int out_size, void* d_ws, size_t ws_size,
                              hipStream_t stream) {
  const float* q = (const float*)d_in[0];
  const float* k = (const float*)d_in[1];
  const float* v = (const float*)d_in[2];
  float* out = (float*)d_out;

  const size_t NT = (size_t)BH * L_ * D_;     // 8388608 floats per tensor
  float* qt = (float*)d_ws;
  float* kt = qt + NT;
  float* vt = kt + NT;
  float* M  = vt + NT;                         // BH*L floats
  int* idx  = (int*)(M + (size_t)BH * L_);     // 4096*25 ints
  int* ssel = idx + L_ * U_PART;               // BH*45 ints (sorted desc per bh)
  float* part = (float*)(ssel + BH * TOPU);    // 1440*32*68 floats (~12.5 MB)

  uint32_t k2a, k2b;
#if JAX_THREEFRY_PARTITIONABLE
  tf2x32(0u, 42u, 0u, 1u, k2a, k2b);
#else
  uint32_t a0, a1, b0, b1;
  tf2x32(0u, 42u, 0u, 2u, a0, a1);
  tf2x32(0u, 42u, 1u, 3u, b0, b1);
  k2a = a1; k2b = b1;
#endif

  transpose_scale<<<dim3(L_ / 64, BH, 3), 256, 0, stream>>>(q, k, v, qt, kt, vt);
#if JAX_THREEFRY_PARTITIONABLE
  sample_idx_kernel<<<(L_ * U_PART + 255) / 256, 256, 0, stream>>>(idx, k2a, k2b);
#else
  sample_idx_kernel<<<(L_ * U_PART / 2 + 255) / 256, 256, 0, stream>>>(idx, k2a, k2b);
#endif
  m_kernel<<<BH * L_ / 16, 256, 0, stream>>>(qt, kt, idx, M);
  topk_kernel<<<BH, 256, 0, stream>>>(M, ssel);
  cumsum_kernel<<<BH * D_, 256, 0, stream>>>(v, out);
  update_partial<<<BH * 16, 256, 0, stream>>>(qt, k, vt, ssel, part);
  update_combine<<<BH * TOPU, 64, 0, stream>>>(part, ssel, out);
}